// Round 9
// baseline (1979.654 us; speedup 1.0000x reference)
//
#include <hip/hip_runtime.h>

// Problem constants (fixed by reference setup_inputs)
#define NB    16              // batch
#define CIN_  64              // input channels of x
#define COUT_ 128             // channels of z / output
#define PLANE_ 1024           // 32*32
#define DDIM  (COUT_*PLANE_)  // 131072
#define BDTOT ((size_t)NB*DDIM) // 2097152
#define KMAX  20              // Broyden threshold
#define SMAX  16              // split-K for dots
#define SEG   (DDIM / SMAX)   // 8192
#define GRP8  (SEG / 8)       // 1024 8-elem groups per segment
#define CBLK  256             // conv blocks per batch (64 pgrp x 4 coT)

typedef short  bfrag __attribute__((ext_vector_type(8)));  // 8 bf16 (4 VGPRs)
typedef float  ffrag __attribute__((ext_vector_type(4)));  // 4 fp32 acc

// bf16 <-> fp32 helpers (RNE)
__device__ __forceinline__ float bf2f(unsigned short h) {
    return __uint_as_float(((unsigned int)h) << 16);
}
__device__ __forceinline__ unsigned short f2bf(float f) {
    unsigned int u = __float_as_uint(f);
    u = (u + 0x7FFFu + ((u >> 16) & 1u)) >> 16;
    return (unsigned short)u;
}
__device__ __forceinline__ void bf2x(unsigned int w, float& lo, float& hi) {
    lo = __uint_as_float(w << 16);
    hi = __uint_as_float(w & 0xffff0000u);
}
__device__ __forceinline__ unsigned int packbf(float lo, float hi) {
    return ((unsigned int)f2bf(hi) << 16) | (unsigned int)f2bf(lo);
}
__device__ __forceinline__ void ub4(ushort4 a, float* f) {
    f[0] = bf2f(a.x); f[1] = bf2f(a.y); f[2] = bf2f(a.z); f[3] = bf2f(a.w);
}
__device__ __forceinline__ ushort4 pk4(const float* f) {
    ushort4 r; r.x = f2bf(f[0]); r.y = f2bf(f[1]); r.z = f2bf(f[2]); r.w = f2bf(f[3]);
    return r;
}
__device__ __forceinline__ void ub8(uint4 a, float* f) {
    bf2x(a.x, f[0], f[1]); bf2x(a.y, f[2], f[3]);
    bf2x(a.z, f[4], f[5]); bf2x(a.w, f[6], f[7]);
}
__device__ __forceinline__ float wred(float v) {
    #pragma unroll
    for (int m = 32; m > 0; m >>= 1) v += __shfl_xor(v, m, 64);
    return v;
}

// ---------------------------------------------------------------------------
// Half-tile MFMA conv core: one wave = 32co x 16px. pgrp 0..63 selects
// (hrow = pgrp>>1, wbase = (pgrp&1)*16). 2 acc frags (co 0-15 / 16-31).
// ---------------------------------------------------------------------------
template<int CIN>
__device__ __forceinline__ void conv_core16(
    const unsigned short* __restrict__ zb, const unsigned short* __restrict__ Wt,
    int hrow, int wbase, int co_base, int n, int col, int quad, ffrag accs[2])
{
    const bfrag bzero = {0,0,0,0,0,0,0,0};
    const int w = wbase + col;
    const size_t zbase = (size_t)n * PLANE_ * CIN;
    #pragma unroll
    for (int tap = 0; tap < 9; ++tap) {
        const int dh = tap / 3 - 1, dw = tap % 3 - 1;
        const int sh = hrow + dh, sw = w + dw;
        const bool v = ((unsigned)sh < 32u) && ((unsigned)sw < 32u);
        const int sp = v ? (sh * 32 + sw) : (hrow * 32 + w);
        const unsigned short* z = zb + zbase + (size_t)sp * CIN + quad * 8;
        const unsigned short* wr0 = Wt + ((size_t)tap * COUT_ + co_base + col) * CIN + quad * 8;
        const unsigned short* wr1 = wr0 + 16 * CIN;
        #pragma unroll
        for (int cb = 0; cb < CIN; cb += 32) {
            bfrag a0 = *(const bfrag*)(wr0 + cb);
            bfrag a1 = *(const bfrag*)(wr1 + cb);
            bfrag bf = *(const bfrag*)(z + cb);
            if (!v) bf = bzero;
            accs[0] = __builtin_amdgcn_mfma_f32_16x16x32_bf16(a0, bf, accs[0], 0, 0, 0);
            accs[1] = __builtin_amdgcn_mfma_f32_16x16x32_bf16(a1, bf, accs[1], 0, 0, 0);
        }
    }
}

// ---------------------------------------------------------------------------
// ux = conv(x,U) + b : fp32 ux + bf16 uxb. grid (64,4,NB), 64 thr.
// ---------------------------------------------------------------------------
__global__ __launch_bounds__(64) void conv_ux_kernel(
    const unsigned short* __restrict__ xinb, const unsigned short* __restrict__ WU,
    const float* __restrict__ bias, float* __restrict__ ux,
    unsigned short* __restrict__ uxb)
{
    const int pgrp = blockIdx.x, coT = blockIdx.y, n = blockIdx.z;
    const int hrow = pgrp >> 1, wbase = (pgrp & 1) * 16;
    const int lane = threadIdx.x, col = lane & 15, quad = lane >> 4;
    ffrag accs[2] = {{0.f,0.f,0.f,0.f},{0.f,0.f,0.f,0.f}};
    conv_core16<CIN_>(xinb, WU, hrow, wbase, coT * 32, n, col, quad, accs);
    const int px = hrow * 32 + wbase + col;
    #pragma unroll
    for (int f = 0; f < 2; ++f) {
        const int co = coT * 32 + f * 16 + quad * 4;
        const size_t o = ((size_t)n * PLANE_ + px) * COUT_ + co;
        float4 bv = *(const float4*)(bias + co);
        float r[4] = {accs[f][0] + bv.x, accs[f][1] + bv.y, accs[f][2] + bv.z, accs[f][3] + bv.w};
        *(float4*)(ux + o) = make_float4(r[0], r[1], r[2], r[3]);
        *(ushort4*)(uxb + o) = pk4(r);
    }
}

// ---------------------------------------------------------------------------
// Broyden conv: g = relu(conv(z,A)+ux) - x ; dgx = g - gx_old (gx in place)
// + 6 state scalars: 0:dx.dgx 1:dx.g 2:g.g 3:dx.dx 4:dgx.dgx 5:dgx.g
// cparts[(row*NB+n)*CBLK + blk], blk = pgrp*4+coT. grid (64,4,NB), 64 thr.
// ---------------------------------------------------------------------------
__global__ __launch_bounds__(64) void conv_bro_kernel(
    const unsigned short* __restrict__ zb, const unsigned short* __restrict__ WA,
    const unsigned short* __restrict__ uxb, const float* __restrict__ xv,
    unsigned short* gxb,                       // rw (old -> new)
    const unsigned short* __restrict__ updb,   // dx
    unsigned short* __restrict__ dgxb,
    float* __restrict__ cparts)
{
    const int pgrp = blockIdx.x, coT = blockIdx.y, n = blockIdx.z;
    const int hrow = pgrp >> 1, wbase = (pgrp & 1) * 16;
    const int lane = threadIdx.x, col = lane & 15, quad = lane >> 4;
    ffrag accs[2] = {{0.f,0.f,0.f,0.f},{0.f,0.f,0.f,0.f}};
    conv_core16<COUT_>(zb, WA, hrow, wbase, coT * 32, n, col, quad, accs);

    const int px = hrow * 32 + wbase + col;
    float s0 = 0.f, s1 = 0.f, s2 = 0.f, s3 = 0.f, s4 = 0.f, s5 = 0.f;
    #pragma unroll
    for (int f = 0; f < 2; ++f) {
        const int co = coT * 32 + f * 16 + quad * 4;
        const size_t o = ((size_t)n * PLANE_ + px) * COUT_ + co;
        float uxv[4], gov[4], udv[4];
        ub4(*(const ushort4*)(uxb + o), uxv);
        ub4(*(const ushort4*)(gxb + o), gov);
        ub4(*(const ushort4*)(updb + o), udv);
        float4 xc = *(const float4*)(xv + o);
        float g[4], dgv[4];
        #pragma unroll
        for (int r = 0; r < 4; ++r) {
            float tv = accs[f][r] + uxv[r];
            tv = tv > 0.f ? tv : 0.f;
            g[r] = tv - (&xc.x)[r];
            dgv[r] = g[r] - gov[r];
            s0 += udv[r] * dgv[r];
            s1 += udv[r] * g[r];
            s2 += g[r] * g[r];
            s3 += udv[r] * udv[r];
            s4 += dgv[r] * dgv[r];
            s5 += dgv[r] * g[r];
        }
        *(ushort4*)(gxb + o)  = pk4(g);
        *(ushort4*)(dgxb + o) = pk4(dgv);
    }
    s0 = wred(s0); s1 = wred(s1); s2 = wred(s2);
    s3 = wred(s3); s4 = wred(s4); s5 = wred(s5);
    if (lane == 0) {
        const int blk = pgrp * 4 + coT;
        cparts[((size_t)0 * NB + n) * CBLK + blk] = s0;
        cparts[((size_t)1 * NB + n) * CBLK + blk] = s1;
        cparts[((size_t)2 * NB + n) * CBLK + blk] = s2;
        cparts[((size_t)3 * NB + n) * CBLK + blk] = s3;
        cparts[((size_t)4 * NB + n) * CBLK + blk] = s4;
        cparts[((size_t)5 * NB + n) * CBLK + blk] = s5;
    }
}

// ---------------------------------------------------------------------------
// Final recompute: out = relu(conv(best,A) + ux_fp32)  -> NCHW
// ---------------------------------------------------------------------------
__global__ __launch_bounds__(64) void conv_final_kernel(
    const unsigned short* __restrict__ bestzb, const unsigned short* __restrict__ WA,
    const float* __restrict__ ux, float* __restrict__ out)
{
    const int pgrp = blockIdx.x, coT = blockIdx.y, n = blockIdx.z;
    const int hrow = pgrp >> 1, wbase = (pgrp & 1) * 16;
    const int lane = threadIdx.x, col = lane & 15, quad = lane >> 4;
    ffrag accs[2] = {{0.f,0.f,0.f,0.f},{0.f,0.f,0.f,0.f}};
    conv_core16<COUT_>(bestzb, WA, hrow, wbase, coT * 32, n, col, quad, accs);
    const int px = hrow * 32 + wbase + col;
    #pragma unroll
    for (int f = 0; f < 2; ++f) {
        const int co = coT * 32 + f * 16 + quad * 4;
        const size_t o = ((size_t)n * PLANE_ + px) * COUT_ + co;
        float4 uv = *(const float4*)(ux + o);
        #pragma unroll
        for (int r = 0; r < 4; ++r) {
            float t = accs[f][r] + (&uv.x)[r];
            out[((size_t)n * COUT_ + co + r) * PLANE_ + px] = t > 0.f ? t : 0.f;
        }
    }
}

// ---------------------------------------------------------------------------
// One-time prep
// ---------------------------------------------------------------------------
#define NWA (9 * 128 * 128)
#define NWU (9 * 128 * 64)
__global__ __launch_bounds__(256) void prep_w_kernel(
    const float* __restrict__ A, const float* __restrict__ U,
    unsigned short* __restrict__ WA, unsigned short* __restrict__ WU)
{
    int idx = blockIdx.x * 256 + threadIdx.x;
    if (idx < NWA) {
        int tap = idx / (128 * 128), r = idx % (128 * 128);
        int co = r >> 7, ci = r & 127;
        WA[idx] = f2bf(A[(co * 128 + ci) * 9 + tap]);
    } else if (idx < NWA + NWU) {
        int j = idx - NWA;
        int tap = j / (128 * 64), r = j % (128 * 64);
        int co = r >> 6, ci = r & 63;
        WU[j] = f2bf(U[(co * 64 + ci) * 9 + tap]);
    }
}

__global__ __launch_bounds__(256) void prep_xin_kernel(
    const float* __restrict__ x, unsigned short* __restrict__ xb)
{
    int idx = blockIdx.x * 256 + threadIdx.x;   // over 16*1024*64
    int n = idx >> 16, r = idx & 65535;
    int px = r >> 6, ci = r & 63;
    xb[idx] = f2bf(x[(n * 64 + ci) * 1024 + px]);
}

__global__ __launch_bounds__(256) void fill0_kernel(float* __restrict__ a)
{
    size_t i = ((size_t)blockIdx.x * 256 + threadIdx.x) * 4;
    *(float4*)(a + i) = make_float4(0.f, 0.f, 0.f, 0.f);
}

// ---------------------------------------------------------------------------
// Init: gx0 = upd0 = relu(ux) (bf16-rounded), x1 = same (fp32), zb mirror,
// per-block obj partial -> objinit[1024].
// ---------------------------------------------------------------------------
__global__ __launch_bounds__(256) void ew_init_kernel(
    const float* __restrict__ ux, unsigned short* __restrict__ gxb,
    unsigned short* __restrict__ updb, float* __restrict__ xv,
    unsigned short* __restrict__ zb, float* __restrict__ objinit)
{
    const int tid = threadIdx.x;
    size_t i = ((size_t)blockIdx.x * 256 + tid) * 8;
    float rr[8];
    float ob = 0.f;
    #pragma unroll
    for (int h = 0; h < 2; ++h) {
        float4 u = *(const float4*)(ux + i + h * 4);
        #pragma unroll
        for (int r = 0; r < 4; ++r) {
            float v = (&u.x)[r];
            v = v > 0.f ? v : 0.f;
            v = bf2f(f2bf(v));           // round once, use consistently
            rr[h*4+r] = v;
            ob += v * v;
        }
    }
    uint4 m = {packbf(rr[0],rr[1]), packbf(rr[2],rr[3]), packbf(rr[4],rr[5]), packbf(rr[6],rr[7])};
    *(uint4*)(gxb  + i) = m;
    *(uint4*)(updb + i) = m;
    *(uint4*)(zb   + i) = m;
    #pragma unroll
    for (int h = 0; h < 2; ++h)
        *(float4*)(xv + i + h * 4) = make_float4(rr[h*4+0], rr[h*4+1], rr[h*4+2], rr[h*4+3]);

    __shared__ float so[256];
    so[tid] = ob;
    __syncthreads();
    for (int s = 128; s > 0; s >>= 1) {
        if (tid < s) so[tid] += so[tid + s];
        __syncthreads();
    }
    if (tid == 0) objinit[blockIdx.x] = so[0];
}

// ---------------------------------------------------------------------------
// Split-K dots vs dgx ONLY: y<k: q_i = v_i.dgx ; y>=k: r_i = u_i.dgx
// grid (NB, 2k, SMAX), 256 thr. tparts[(y*NB+b)*SMAX+s]
// ---------------------------------------------------------------------------
__global__ __launch_bounds__(256) void dots_kernel(
    const unsigned short* __restrict__ Us, const unsigned short* __restrict__ VTs,
    const unsigned short* __restrict__ dgxb,
    float* __restrict__ tparts, int k)
{
    const int b = blockIdx.x, y = blockIdx.y, s = blockIdx.z;
    const int tid = threadIdx.x;
    const size_t segbase = (size_t)b * DDIM + (size_t)s * SEG;
    const unsigned short* M = (y < k) ? (VTs + (size_t)y * BDTOT)
                                      : (Us + (size_t)(y - k) * BDTOT);
    const uint4* m8 = (const uint4*)(M + segbase);
    const uint4* d8 = (const uint4*)(dgxb + segbase);
    float s0 = 0.f;
    #pragma unroll
    for (int it = 0; it < GRP8 / 256; ++it) {
        int g = it * 256 + tid;
        float mv[8], dv[8];
        ub8(m8[g], mv); ub8(d8[g], dv);
        #pragma unroll
        for (int j = 0; j < 8; ++j) s0 = fmaf(mv[j], dv[j], s0);
    }
    __shared__ float r0[256];
    r0[tid] = s0;
    __syncthreads();
    for (int st = 128; st > 0; st >>= 1) {
        if (tid < st) r0[tid] += r0[tid + st];
        __syncthreads();
    }
    if (tid == 0) tparts[((size_t)y * NB + b) * SMAX + s] = r0[0];
}

// ---------------------------------------------------------------------------
// Fused big pass. Every block redundantly folds (deterministic): q_i,r_i
// (tparts), t_i = q_i + tp_r, h_i = r_i + hp_r, p_i (parr_r), 6 state
// scalars (cparts), den, c, flag. Main: one history read, write new rows,
// advance x, mirrors, best snapshot. Block (0,b): O(k^2) recurrences for
// next-iter p (Gram UU) and prev-dot arrays tp_w/hp_w; obj_arr.
// grid = (64, NB), 256 thr, 8 elems/thread.
// ---------------------------------------------------------------------------
__global__ __launch_bounds__(256) void pass2_kernel(
    unsigned short* __restrict__ Us, unsigned short* __restrict__ VTs,
    unsigned short* updb,                 // rw: dx in, new update out
    const unsigned short* __restrict__ dgxb, const unsigned short* __restrict__ gxb,
    float* xv, unsigned short* __restrict__ zb, unsigned short* __restrict__ bestzb,
    const float* __restrict__ tparts, const float* __restrict__ cparts,
    const float* __restrict__ objinit,
    const float* __restrict__ parr_r, float* __restrict__ parr_w,
    const float* __restrict__ tp_r, float* __restrict__ tp_w,
    const float* __restrict__ hp_r, float* __restrict__ hp_w,
    float* __restrict__ UU, float* __restrict__ obj_arr, int k)
{
    const int b = blockIdx.y;
    const int bx = blockIdx.x;
    const int tid = threadIdx.x;
    const int lane = tid & 63, wv = tid >> 6;

    __shared__ float sq[KMAX], st[KMAX], sp[KMAX], sr[KMAX], sh[KMAX], UUk[KMAX];
    __shared__ float sS[5];     // 0:dd 1:dg1 2:dxdx 3:dgdg 4:dgg
    __shared__ float sden, sc, sflag, sobj, srk;
    __shared__ float red[256];

    // ---- fold obj_cur = sum over cparts row 2 (all NB) ----
    {
        float o = 0.f;
        const float* OB = cparts + (size_t)2 * NB * CBLK;
        for (int j = tid; j < NB * CBLK; j += 256) o += OB[j];
        red[tid] = o;
        __syncthreads();
        for (int s = 128; s > 0; s >>= 1) {
            if (tid < s) red[tid] += red[tid + s];
            __syncthreads();
        }
        if (tid == 0) sobj = red[0];
        __syncthreads();
    }
    // ---- k==0: fold obj0 from objinit ----
    float obj0 = 0.f;
    if (k == 0) {
        float o = 0.f;
        for (int j = tid; j < 1024; j += 256) o += objinit[j];
        red[tid] = o;
        __syncthreads();
        for (int s = 128; s > 0; s >>= 1) {
            if (tid < s) red[tid] += red[tid + s];
            __syncthreads();
        }
        obj0 = red[0];
        __syncthreads();
    }

    // ---- per-row folds ----
    if (tid < k) {
        float qv = 0.f, rv = 0.f;
        #pragma unroll
        for (int s = 0; s < SMAX; ++s) {
            qv += tparts[((size_t)tid * NB + b) * SMAX + s];
            rv += tparts[((size_t)(k + tid) * NB + b) * SMAX + s];
        }
        sq[tid] = qv; sr[tid] = rv;
        st[tid] = qv + tp_r[b * KMAX + tid];
        sh[tid] = rv + hp_r[b * KMAX + tid];
        sp[tid] = parr_r[b * KMAX + tid];
    }
    // wave folds of cparts rows (per-batch b)
    if (wv == 1) {
        float a0 = 0.f, a1 = 0.f;
        for (int j = lane; j < CBLK; j += 64) {
            a0 += cparts[((size_t)0 * NB + b) * CBLK + j];
            a1 += cparts[((size_t)3 * NB + b) * CBLK + j];
        }
        a0 = wred(a0); a1 = wred(a1);
        if (lane == 0) { sS[0] = a0; sS[2] = a1; }
    } else if (wv == 2) {
        float a0 = 0.f, a1 = 0.f;
        for (int j = lane; j < CBLK; j += 64) {
            a0 += cparts[((size_t)1 * NB + b) * CBLK + j];
            a1 += cparts[((size_t)4 * NB + b) * CBLK + j];
        }
        a0 = wred(a0); a1 = wred(a1);
        if (lane == 0) { sS[1] = a0; sS[3] = a1; }
    } else if (wv == 3) {
        float a0 = 0.f;
        for (int j = lane; j < CBLK; j += 64)
            a0 += cparts[((size_t)5 * NB + b) * CBLK + j];
        a0 = wred(a0);
        if (lane == 0) sS[4] = a0;
    }
    __syncthreads();

    if (tid == 0) {
        float pq = 0.f, pt = 0.f;
        for (int i = 0; i < k; ++i) { pq += sp[i] * sq[i]; pt += sp[i] * st[i]; }
        float den = -sS[0] + pq;
        if (fabsf(den) < 1e-9f) den = 1e-9f;
        sden = den;
        float rk = -sS[1] + pt;
        srk = rk;
        sc = rk / den;
        float best;
        if (k == 0) best = obj0;
        else {
            best = obj_arr[0];
            for (int j = 1; j <= k; ++j) best = fminf(best, obj_arr[j]);
        }
        sflag = (sobj < best) ? 1.f : 0.f;
    }
    __syncthreads();

    // ------------------- main vector pass -------------------
    const size_t base = (size_t)b * DDIM + ((size_t)bx * 256 + tid) * 8;
    float xd[8], dg[8], gv[8];
    ub8(*(const uint4*)(updb + base), xd);
    ub8(*(const uint4*)(dgxb + base), dg);
    ub8(*(const uint4*)(gxb  + base), gv);

    float S1[8], S2[8], SV[8];
    #pragma unroll
    for (int j = 0; j < 8; ++j) { S1[j] = 0.f; S2[j] = 0.f; SV[j] = 0.f; }

    int i = 0;
    for (; i + 1 < k; i += 2) {
        uint4 ru0 = *(const uint4*)(Us  + (size_t)i * BDTOT + base);
        uint4 rv0 = *(const uint4*)(VTs + (size_t)i * BDTOT + base);
        uint4 ru1 = *(const uint4*)(Us  + (size_t)(i + 1) * BDTOT + base);
        uint4 rv1 = *(const uint4*)(VTs + (size_t)(i + 1) * BDTOT + base);
        float u0[8], v0[8], u1[8], v1[8];
        ub8(ru0, u0); ub8(rv0, v0); ub8(ru1, u1); ub8(rv1, v1);
        float q0 = sq[i], t0 = st[i], p0 = sp[i];
        float q1 = sq[i+1], t1 = st[i+1], p1 = sp[i+1];
        #pragma unroll
        for (int j = 0; j < 8; ++j) {
            S1[j] = fmaf(q0, u0[j], fmaf(q1, u1[j], S1[j]));
            S2[j] = fmaf(t0, u0[j], fmaf(t1, u1[j], S2[j]));
            SV[j] = fmaf(p0, v0[j], fmaf(p1, v1[j], SV[j]));
        }
    }
    if (i < k) {
        float uvals[8], vvals[8];
        ub8(*(const uint4*)(Us  + (size_t)i * BDTOT + base), uvals);
        ub8(*(const uint4*)(VTs + (size_t)i * BDTOT + base), vvals);
        float qi = sq[i], ti = st[i], pi = sp[i];
        #pragma unroll
        for (int j = 0; j < 8; ++j) {
            S1[j] = fmaf(qi, uvals[j], S1[j]);
            S2[j] = fmaf(ti, uvals[j], S2[j]);
            SV[j] = fmaf(pi, vvals[j], SV[j]);
        }
    }

    float vk[8], uk[8], up[8];
    #pragma unroll
    for (int j = 0; j < 8; ++j) {
        vk[j] = -xd[j] + SV[j];
        uk[j] = (xd[j] + dg[j] - S1[j]) / sden;
        up[j] = gv[j] - sc * (xd[j] + dg[j]) - S2[j] + sc * S1[j];
    }
    uint4 vks = {packbf(vk[0],vk[1]), packbf(vk[2],vk[3]), packbf(vk[4],vk[5]), packbf(vk[6],vk[7])};
    uint4 uks = {packbf(uk[0],uk[1]), packbf(uk[2],uk[3]), packbf(uk[4],uk[5]), packbf(uk[6],uk[7])};
    *(uint4*)(VTs + (size_t)k * BDTOT + base) = vks;
    *(uint4*)(Us  + (size_t)k * BDTOT + base) = uks;

    uint4 upw = {packbf(up[0],up[1]), packbf(up[2],up[3]), packbf(up[4],up[5]), packbf(up[6],up[7])};
    *(uint4*)(updb + base) = upw;
    float upr[8];
    ub8(upw, upr);

    float xc[8];
    #pragma unroll
    for (int h = 0; h < 2; ++h) {
        float4 a = *(const float4*)(xv + base + h * 4);
        xc[h*4+0]=a.x; xc[h*4+1]=a.y; xc[h*4+2]=a.z; xc[h*4+3]=a.w;
    }
    if (sflag != 0.f) {
        uint4 bz = {packbf(xc[0],xc[1]), packbf(xc[2],xc[3]),
                    packbf(xc[4],xc[5]), packbf(xc[6],xc[7])};
        *(uint4*)(bestzb + base) = bz;
    }
    float xn[8];
    #pragma unroll
    for (int j = 0; j < 8; ++j) xn[j] = xc[j] + upr[j];
    #pragma unroll
    for (int h = 0; h < 2; ++h)
        *(float4*)(xv + base + h * 4) = make_float4(xn[h*4+0], xn[h*4+1], xn[h*4+2], xn[h*4+3]);
    uint4 zn = {packbf(xn[0],xn[1]), packbf(xn[2],xn[3]), packbf(xn[4],xn[5]), packbf(xn[6],xn[7])};
    *(uint4*)(zb + base) = zn;

    // ------------- scalar recurrences (block bx==0 only) -------------
    if (bx == 0) {
        const float den = sden, cc = sc;
        // UUk[l] = u_k . u_l = ((p_l + r_l) - sum_j q_j UU[b][j][l]) / den
        if (tid < k) {
            float acc = sp[tid] + sr[tid];
            for (int j = 0; j < k; ++j)
                acc -= sq[j] * UU[((size_t)b * KMAX + j) * KMAX + tid];
            UUk[tid] = acc / den;
        }
        __syncthreads();
        if (tid == 0) {
            float ww = sS[2] + 2.f * sS[0] + sS[3];   // w.w
            float wg = sS[1] + sS[4];                 // w.g
            float sumqh = 0.f, sumqpr = 0.f, sumqU = 0.f;
            for (int j = 0; j < k; ++j) {
                sumqh += sq[j] * sh[j];
                sumqpr += sq[j] * (sp[j] + sr[j]);
                sumqU += sq[j] * UUk[j];
            }
            float ug = (wg - sumqh) / den;            // u_k.g
            float uw = (ww - sumqpr) / den;           // u_k.w
            float UUkk = (uw - sumqU) / den;
            for (int l = 0; l < k; ++l) {
                UU[((size_t)b * KMAX + k) * KMAX + l] = UUk[l];
                UU[((size_t)b * KMAX + l) * KMAX + k] = UUk[l];
            }
            UU[((size_t)b * KMAX + k) * KMAX + k] = UUkk;
            // p_next for new row k
            float acc = ug - cc * uw;
            for (int l = 0; l < k; ++l)
                acc -= (st[l] - cc * sq[l]) * UUk[l];
            parr_w[b * KMAX + k] = acc;
            // prev-dot arrays for new row k
            tp_w[b * KMAX + k] = srk;                 // v_k.g
            hp_w[b * KMAX + k] = ug;                  // u_k.g
            if (b == 0) {
                if (k == 0) obj_arr[0] = obj0;
                obj_arr[k + 1] = sobj;
            }
        }
        if (tid < k) {
            // p_next_i = h_i - c (p_i + r_i) - sum_l s_l UU[b][i][l]
            float acc = sh[tid] - cc * (sp[tid] + sr[tid]);
            for (int l = 0; l < k; ++l)
                acc -= (st[l] - cc * sq[l]) * UU[((size_t)b * KMAX + tid) * KMAX + l];
            parr_w[b * KMAX + tid] = acc;
            tp_w[b * KMAX + tid] = st[tid];
            hp_w[b * KMAX + tid] = sh[tid];
        }
    }
}

// ---------------------------------------------------------------------------
// Last iteration: fold obj, flag vs obj_arr[0..KMAX-1], conditional copy.
// ---------------------------------------------------------------------------
__global__ __launch_bounds__(256) void bestfinal_kernel(
    const float* __restrict__ cparts, const float* __restrict__ obj_arr,
    const unsigned short* __restrict__ zb, unsigned short* __restrict__ bestzb)
{
    const int tid = threadIdx.x;
    __shared__ float red[256];
    __shared__ float sflag;
    float o = 0.f;
    const float* OB = cparts + (size_t)2 * NB * CBLK;
    for (int j = tid; j < NB * CBLK; j += 256) o += OB[j];
    red[tid] = o;
    __syncthreads();
    for (int s = 128; s > 0; s >>= 1) {
        if (tid < s) red[tid] += red[tid + s];
        __syncthreads();
    }
    if (tid == 0) {
        float best = obj_arr[0];
        for (int j = 1; j < KMAX; ++j) best = fminf(best, obj_arr[j]);
        sflag = (red[0] < best) ? 1.f : 0.f;
    }
    __syncthreads();
    if (sflag == 0.f) return;
    size_t i = ((size_t)blockIdx.x * 256 + tid) * 8;
    *(uint4*)(bestzb + i) = *(const uint4*)(zb + i);
}

// ---------------------------------------------------------------------------
extern "C" void kernel_launch(void* const* d_in, const int* in_sizes, int n_in,
                              void* d_out, int out_size, void* d_ws, size_t ws_size,
                              hipStream_t stream)
{
    (void)in_sizes; (void)n_in; (void)out_size; (void)ws_size;
    const float* x  = (const float*)d_in[0];   // [16,64,32,32]
    const float* A  = (const float*)d_in[1];   // [128,128,3,3]
    const float* U  = (const float*)d_in[2];   // [128,64,3,3]
    const float* bb = (const float*)d_in[3];   // [128]
    float* out = (float*)d_out;

    char* w = (char*)d_ws;
    size_t off = 0;
    auto alloc = [&](size_t bytes) -> void* {
        void* pp = (void*)(w + off);
        off += (bytes + 255) & ~(size_t)255;
        return pp;
    };
    const size_t BDB  = BDTOT * sizeof(float);  // 8 MB
    const size_t BDH  = BDTOT * 2;              // 4 MB (bf16)
    float* ux    = (float*)alloc(BDB);          // fp32 (final recompute)
    float* xv    = (float*)alloc(BDB);          // fp32 iterate accumulator
    unsigned short* uxb    = (unsigned short*)alloc(BDH);
    unsigned short* gxb    = (unsigned short*)alloc(BDH);
    unsigned short* updb   = (unsigned short*)alloc(BDH);
    unsigned short* dgxb   = (unsigned short*)alloc(BDH);
    unsigned short* zb     = (unsigned short*)alloc(BDH);
    unsigned short* bestzb = (unsigned short*)alloc(BDH);
    unsigned short* xinb   = (unsigned short*)alloc((size_t)NB * PLANE_ * CIN_ * 2);
    unsigned short* WA     = (unsigned short*)alloc((size_t)NWA * 2);
    unsigned short* WU     = (unsigned short*)alloc((size_t)NWU * 2);
    unsigned short* Us  = (unsigned short*)alloc((size_t)KMAX * BDTOT * 2); // 84 MB
    unsigned short* VTs = (unsigned short*)alloc((size_t)KMAX * BDTOT * 2); // 84 MB
    float* cparts = (float*)alloc((size_t)6 * NB * CBLK * sizeof(float));
    float* tparts = (float*)alloc((size_t)2 * KMAX * NB * SMAX * sizeof(float));
    float* objinit= (float*)alloc(1024 * sizeof(float));
    float* parr0 = (float*)alloc(NB * KMAX * sizeof(float));
    float* parr1 = (float*)alloc(NB * KMAX * sizeof(float));
    float* tp0   = (float*)alloc(NB * KMAX * sizeof(float));
    float* tp1   = (float*)alloc(NB * KMAX * sizeof(float));
    float* hp0   = (float*)alloc(NB * KMAX * sizeof(float));
    float* hp1   = (float*)alloc(NB * KMAX * sizeof(float));
    float* UU    = (float*)alloc((size_t)NB * KMAX * KMAX * sizeof(float));
    float* obj_arr = (float*)alloc((KMAX + 1) * sizeof(float));

    const dim3 CG(64, 4, NB);                   // conv grid, 64-thr blocks
    const int I8WG = (int)(BDTOT / (256 * 8));  // 1024 blocks, 8 elems/thread

    // -------- one-time prep --------
    prep_w_kernel<<<(NWA + NWU + 255) / 256, 256, 0, stream>>>(A, U, WA, WU);
    prep_xin_kernel<<<(NB * PLANE_ * CIN_) / 256, 256, 0, stream>>>(x, xinb);
    fill0_kernel<<<(int)(BDH / (256 * 16)), 256, 0, stream>>>((float*)bestzb); // best = x0 = 0

    conv_ux_kernel<<<CG, 64, 0, stream>>>(xinb, WU, bb, ux, uxb);
    ew_init_kernel<<<I8WG, 256, 0, stream>>>(ux, gxb, updb, xv, zb, objinit);

    float* parr[2] = {parr0, parr1};
    float* tp[2]   = {tp0, tp1};
    float* hp[2]   = {hp0, hp1};
    for (int k = 0; k < KMAX; ++k) {
        conv_bro_kernel<<<CG, 64, 0, stream>>>(zb, WA, uxb, xv, gxb, updb, dgxb, cparts);
        if (k < KMAX - 1) {
            if (k > 0)
                dots_kernel<<<dim3(NB, 2 * k, SMAX), 256, 0, stream>>>(
                    Us, VTs, dgxb, tparts, k);
            pass2_kernel<<<dim3(DDIM / 2048, NB), 256, 0, stream>>>(
                Us, VTs, updb, dgxb, gxb, xv, zb, bestzb,
                tparts, cparts, objinit,
                parr[k & 1], parr[(k + 1) & 1],
                tp[k & 1], tp[(k + 1) & 1],
                hp[k & 1], hp[(k + 1) & 1],
                UU, obj_arr, k);
        } else {
            bestfinal_kernel<<<I8WG, 256, 0, stream>>>(cparts, obj_arr, zb, bestzb);
        }
    }

    // zn = relu(conv(best,A) + ux_fp32) -> NCHW out
    conv_final_kernel<<<CG, 64, 0, stream>>>(bestzb, WA, ux, out);
}

// Round 10
// 1614.927 us; speedup vs baseline: 1.2258x; 1.2258x over previous
//
#include <hip/hip_runtime.h>

// Problem constants (fixed by reference setup_inputs)
#define NB    16              // batch
#define CIN_  64              // input channels of x
#define COUT_ 128             // channels of z / output
#define PLANE_ 1024           // 32*32
#define DDIM  (COUT_*PLANE_)  // 131072
#define BDTOT ((size_t)NB*DDIM) // 2097152
#define KMAX  20              // Broyden threshold
#define SMAX  16              // split-K for dots
#define SEG   (DDIM / SMAX)   // 8192
#define GRP8  (SEG / 8)       // 1024 8-elem groups per segment
#define CBLK  128             // conv blocks per batch (32 hrow x 4 coT)

typedef short  bfrag __attribute__((ext_vector_type(8)));  // 8 bf16 (4 VGPRs)
typedef float  ffrag __attribute__((ext_vector_type(4)));  // 4 fp32 acc

// bf16 <-> fp32 helpers (RNE)
__device__ __forceinline__ float bf2f(unsigned short h) {
    return __uint_as_float(((unsigned int)h) << 16);
}
__device__ __forceinline__ unsigned short f2bf(float f) {
    unsigned int u = __float_as_uint(f);
    u = (u + 0x7FFFu + ((u >> 16) & 1u)) >> 16;
    return (unsigned short)u;
}
__device__ __forceinline__ void bf2x(unsigned int w, float& lo, float& hi) {
    lo = __uint_as_float(w << 16);
    hi = __uint_as_float(w & 0xffff0000u);
}
__device__ __forceinline__ unsigned int packbf(float lo, float hi) {
    return ((unsigned int)f2bf(hi) << 16) | (unsigned int)f2bf(lo);
}
__device__ __forceinline__ void ub4(ushort4 a, float* f) {
    f[0] = bf2f(a.x); f[1] = bf2f(a.y); f[2] = bf2f(a.z); f[3] = bf2f(a.w);
}
__device__ __forceinline__ ushort4 pk4(const float* f) {
    ushort4 r; r.x = f2bf(f[0]); r.y = f2bf(f[1]); r.z = f2bf(f[2]); r.w = f2bf(f[3]);
    return r;
}
__device__ __forceinline__ void ub8(uint4 a, float* f) {
    bf2x(a.x, f[0], f[1]); bf2x(a.y, f[2], f[3]);
    bf2x(a.z, f[4], f[5]); bf2x(a.w, f[6], f[7]);
}
__device__ __forceinline__ float wred(float v) {
    #pragma unroll
    for (int m = 32; m > 0; m >>= 1) v += __shfl_xor(v, m, 64);
    return v;
}

// ---------------------------------------------------------------------------
// MFMA conv core, 32co x 32px per wave, SOFTWARE-PIPELINED: per 32-ch K-chunk
// issue all 36 independent loads (9 taps x {wa0,wa1,b0,b1}) before the 36
// MFMAs. Grid is latency-limited at 2 waves/SIMD, so the ~180 VGPRs are free.
// ---------------------------------------------------------------------------
template<int CIN>
__device__ __forceinline__ void conv_core(
    const unsigned short* __restrict__ zb, const unsigned short* __restrict__ Wt,
    int hrow, int co_base, int n, int col, int quad, ffrag accs[4])
{
    const bfrag bzero = {0,0,0,0,0,0,0,0};
    const int w0 = col, w1 = col + 16;
    const size_t zbase = (size_t)n * PLANE_ * CIN;
    const unsigned short* zp0[9];
    const unsigned short* zp1[9];
    bool vv0[9], vv1[9];
    #pragma unroll
    for (int tap = 0; tap < 9; ++tap) {
        const int dh = tap / 3 - 1, dw = tap % 3 - 1;
        const int sh = hrow + dh;
        const bool rowok = (unsigned)sh < 32u;
        const int sw0 = w0 + dw, sw1 = w1 + dw;
        vv0[tap] = rowok && (unsigned)sw0 < 32u;
        vv1[tap] = rowok && (unsigned)sw1 < 32u;
        const int sp0 = vv0[tap] ? (sh * 32 + sw0) : (hrow * 32 + w0);
        const int sp1 = vv1[tap] ? (sh * 32 + sw1) : (hrow * 32 + w1);
        zp0[tap] = zb + zbase + (size_t)sp0 * CIN + quad * 8;
        zp1[tap] = zb + zbase + (size_t)sp1 * CIN + quad * 8;
    }
    #pragma unroll
    for (int cb = 0; cb < CIN; cb += 32) {
        bfrag wa0[9], wa1[9], b0[9], b1[9];
        #pragma unroll
        for (int tap = 0; tap < 9; ++tap) {
            const unsigned short* wr0 =
                Wt + ((size_t)tap * COUT_ + co_base + col) * CIN + quad * 8 + cb;
            wa0[tap] = *(const bfrag*)(wr0);
            wa1[tap] = *(const bfrag*)(wr0 + 16 * CIN);
            bfrag t0 = *(const bfrag*)(zp0[tap] + cb);
            bfrag t1 = *(const bfrag*)(zp1[tap] + cb);
            if (!vv0[tap]) t0 = bzero;
            if (!vv1[tap]) t1 = bzero;
            b0[tap] = t0;
            b1[tap] = t1;
        }
        #pragma unroll
        for (int tap = 0; tap < 9; ++tap) {
            accs[0] = __builtin_amdgcn_mfma_f32_16x16x32_bf16(wa0[tap], b0[tap], accs[0], 0, 0, 0);
            accs[1] = __builtin_amdgcn_mfma_f32_16x16x32_bf16(wa0[tap], b1[tap], accs[1], 0, 0, 0);
            accs[2] = __builtin_amdgcn_mfma_f32_16x16x32_bf16(wa1[tap], b0[tap], accs[2], 0, 0, 0);
            accs[3] = __builtin_amdgcn_mfma_f32_16x16x32_bf16(wa1[tap], b1[tap], accs[3], 0, 0, 0);
        }
    }
}

// ---------------------------------------------------------------------------
// ux = conv(x,U) + b : fp32 ux + bf16 uxb. grid (32,4,NB), 64 thr.
// ---------------------------------------------------------------------------
__global__ __launch_bounds__(64) void conv_ux_kernel(
    const unsigned short* __restrict__ xinb, const unsigned short* __restrict__ WU,
    const float* __restrict__ bias, float* __restrict__ ux,
    unsigned short* __restrict__ uxb)
{
    const int hrow = blockIdx.x, coT = blockIdx.y, n = blockIdx.z;
    const int lane = threadIdx.x, col = lane & 15, quad = lane >> 4;
    ffrag accs[4] = {{0.f,0.f,0.f,0.f},{0.f,0.f,0.f,0.f},{0.f,0.f,0.f,0.f},{0.f,0.f,0.f,0.f}};
    conv_core<CIN_>(xinb, WU, hrow, coT * 32, n, col, quad, accs);
    #pragma unroll
    for (int f = 0; f < 4; ++f) {
        const int mt = f >> 1, nt = f & 1;
        const int co = coT * 32 + mt * 16 + quad * 4;
        const int px = hrow * 32 + nt * 16 + col;
        const size_t o = ((size_t)n * PLANE_ + px) * COUT_ + co;
        float4 bv = *(const float4*)(bias + co);
        float r[4] = {accs[f][0] + bv.x, accs[f][1] + bv.y, accs[f][2] + bv.z, accs[f][3] + bv.w};
        *(float4*)(ux + o) = make_float4(r[0], r[1], r[2], r[3]);
        *(ushort4*)(uxb + o) = pk4(r);
    }
}

// ---------------------------------------------------------------------------
// Broyden conv: g = relu(conv(z,A)+ux) - x ; dgx = g - gx_old (gx in place)
// + 6 state scalars: 0:dx.dgx 1:dx.g 2:g.g 3:dx.dx 4:dgx.dgx 5:dgx.g
// cparts[(row*NB+n)*CBLK + blk], blk = hrow*4+coT. grid (32,4,NB), 64 thr.
// ---------------------------------------------------------------------------
__global__ __launch_bounds__(64) void conv_bro_kernel(
    const unsigned short* __restrict__ zb, const unsigned short* __restrict__ WA,
    const unsigned short* __restrict__ uxb, const float* __restrict__ xv,
    unsigned short* gxb,                       // rw (old -> new)
    const unsigned short* __restrict__ updb,   // dx
    unsigned short* __restrict__ dgxb,
    float* __restrict__ cparts)
{
    const int hrow = blockIdx.x, coT = blockIdx.y, n = blockIdx.z;
    const int lane = threadIdx.x, col = lane & 15, quad = lane >> 4;
    ffrag accs[4] = {{0.f,0.f,0.f,0.f},{0.f,0.f,0.f,0.f},{0.f,0.f,0.f,0.f},{0.f,0.f,0.f,0.f}};
    conv_core<COUT_>(zb, WA, hrow, coT * 32, n, col, quad, accs);

    float s0 = 0.f, s1 = 0.f, s2 = 0.f, s3 = 0.f, s4 = 0.f, s5 = 0.f;
    #pragma unroll
    for (int f = 0; f < 4; ++f) {
        const int mt = f >> 1, nt = f & 1;
        const int co = coT * 32 + mt * 16 + quad * 4;
        const int px = hrow * 32 + nt * 16 + col;
        const size_t o = ((size_t)n * PLANE_ + px) * COUT_ + co;
        float uxv[4], gov[4], udv[4];
        ub4(*(const ushort4*)(uxb + o), uxv);
        ub4(*(const ushort4*)(gxb + o), gov);
        ub4(*(const ushort4*)(updb + o), udv);
        float4 xc = *(const float4*)(xv + o);
        float g[4], dgv[4];
        #pragma unroll
        for (int r = 0; r < 4; ++r) {
            float tv = accs[f][r] + uxv[r];
            tv = tv > 0.f ? tv : 0.f;
            g[r] = tv - (&xc.x)[r];
            dgv[r] = g[r] - gov[r];
            s0 += udv[r] * dgv[r];
            s1 += udv[r] * g[r];
            s2 += g[r] * g[r];
            s3 += udv[r] * udv[r];
            s4 += dgv[r] * dgv[r];
            s5 += dgv[r] * g[r];
        }
        *(ushort4*)(gxb + o)  = pk4(g);
        *(ushort4*)(dgxb + o) = pk4(dgv);
    }
    s0 = wred(s0); s1 = wred(s1); s2 = wred(s2);
    s3 = wred(s3); s4 = wred(s4); s5 = wred(s5);
    if (lane == 0) {
        const int blk = hrow * 4 + coT;
        cparts[((size_t)0 * NB + n) * CBLK + blk] = s0;
        cparts[((size_t)1 * NB + n) * CBLK + blk] = s1;
        cparts[((size_t)2 * NB + n) * CBLK + blk] = s2;
        cparts[((size_t)3 * NB + n) * CBLK + blk] = s3;
        cparts[((size_t)4 * NB + n) * CBLK + blk] = s4;
        cparts[((size_t)5 * NB + n) * CBLK + blk] = s5;
    }
}

// ---------------------------------------------------------------------------
// Final recompute: out = relu(conv(best,A) + ux_fp32)  -> NCHW
// ---------------------------------------------------------------------------
__global__ __launch_bounds__(64) void conv_final_kernel(
    const unsigned short* __restrict__ bestzb, const unsigned short* __restrict__ WA,
    const float* __restrict__ ux, float* __restrict__ out)
{
    const int hrow = blockIdx.x, coT = blockIdx.y, n = blockIdx.z;
    const int lane = threadIdx.x, col = lane & 15, quad = lane >> 4;
    ffrag accs[4] = {{0.f,0.f,0.f,0.f},{0.f,0.f,0.f,0.f},{0.f,0.f,0.f,0.f},{0.f,0.f,0.f,0.f}};
    conv_core<COUT_>(bestzb, WA, hrow, coT * 32, n, col, quad, accs);
    #pragma unroll
    for (int f = 0; f < 4; ++f) {
        const int mt = f >> 1, nt = f & 1;
        const int co = coT * 32 + mt * 16 + quad * 4;
        const int px = hrow * 32 + nt * 16 + col;
        const size_t o = ((size_t)n * PLANE_ + px) * COUT_ + co;
        float4 uv = *(const float4*)(ux + o);
        #pragma unroll
        for (int r = 0; r < 4; ++r) {
            float t = accs[f][r] + (&uv.x)[r];
            out[((size_t)n * COUT_ + co + r) * PLANE_ + px] = t > 0.f ? t : 0.f;
        }
    }
}

// ---------------------------------------------------------------------------
// One-time prep
// ---------------------------------------------------------------------------
#define NWA (9 * 128 * 128)
#define NWU (9 * 128 * 64)
__global__ __launch_bounds__(256) void prep_w_kernel(
    const float* __restrict__ A, const float* __restrict__ U,
    unsigned short* __restrict__ WA, unsigned short* __restrict__ WU)
{
    int idx = blockIdx.x * 256 + threadIdx.x;
    if (idx < NWA) {
        int tap = idx / (128 * 128), r = idx % (128 * 128);
        int co = r >> 7, ci = r & 127;
        WA[idx] = f2bf(A[(co * 128 + ci) * 9 + tap]);
    } else if (idx < NWA + NWU) {
        int j = idx - NWA;
        int tap = j / (128 * 64), r = j % (128 * 64);
        int co = r >> 6, ci = r & 63;
        WU[j] = f2bf(U[(co * 64 + ci) * 9 + tap]);
    }
}

__global__ __launch_bounds__(256) void prep_xin_kernel(
    const float* __restrict__ x, unsigned short* __restrict__ xb)
{
    int idx = blockIdx.x * 256 + threadIdx.x;   // over 16*1024*64
    int n = idx >> 16, r = idx & 65535;
    int px = r >> 6, ci = r & 63;
    xb[idx] = f2bf(x[(n * 64 + ci) * 1024 + px]);
}

__global__ __launch_bounds__(256) void fill0_kernel(float* __restrict__ a)
{
    size_t i = ((size_t)blockIdx.x * 256 + threadIdx.x) * 4;
    *(float4*)(a + i) = make_float4(0.f, 0.f, 0.f, 0.f);
}

// ---------------------------------------------------------------------------
// Init: gx0 = upd0 = relu(ux) (bf16-rounded), x1 = same (fp32), zb mirror,
// per-block obj partial -> objinit[1024].
// ---------------------------------------------------------------------------
__global__ __launch_bounds__(256) void ew_init_kernel(
    const float* __restrict__ ux, unsigned short* __restrict__ gxb,
    unsigned short* __restrict__ updb, float* __restrict__ xv,
    unsigned short* __restrict__ zb, float* __restrict__ objinit)
{
    const int tid = threadIdx.x;
    size_t i = ((size_t)blockIdx.x * 256 + tid) * 8;
    float rr[8];
    float ob = 0.f;
    #pragma unroll
    for (int h = 0; h < 2; ++h) {
        float4 u = *(const float4*)(ux + i + h * 4);
        #pragma unroll
        for (int r = 0; r < 4; ++r) {
            float v = (&u.x)[r];
            v = v > 0.f ? v : 0.f;
            v = bf2f(f2bf(v));           // round once, use consistently
            rr[h*4+r] = v;
            ob += v * v;
        }
    }
    uint4 m = {packbf(rr[0],rr[1]), packbf(rr[2],rr[3]), packbf(rr[4],rr[5]), packbf(rr[6],rr[7])};
    *(uint4*)(gxb  + i) = m;
    *(uint4*)(updb + i) = m;
    *(uint4*)(zb   + i) = m;
    #pragma unroll
    for (int h = 0; h < 2; ++h)
        *(float4*)(xv + i + h * 4) = make_float4(rr[h*4+0], rr[h*4+1], rr[h*4+2], rr[h*4+3]);

    __shared__ float so[256];
    so[tid] = ob;
    __syncthreads();
    for (int s = 128; s > 0; s >>= 1) {
        if (tid < s) so[tid] += so[tid + s];
        __syncthreads();
    }
    if (tid == 0) objinit[blockIdx.x] = so[0];
}

// ---------------------------------------------------------------------------
// Split-K dots vs dgx ONLY: y<k: q_i = v_i.dgx ; y>=k: r_i = u_i.dgx
// grid (NB, 2k, SMAX), 256 thr. tparts[(y*NB+b)*SMAX+s]
// ---------------------------------------------------------------------------
__global__ __launch_bounds__(256) void dots_kernel(
    const unsigned short* __restrict__ Us, const unsigned short* __restrict__ VTs,
    const unsigned short* __restrict__ dgxb,
    float* __restrict__ tparts, int k)
{
    const int b = blockIdx.x, y = blockIdx.y, s = blockIdx.z;
    const int tid = threadIdx.x;
    const size_t segbase = (size_t)b * DDIM + (size_t)s * SEG;
    const unsigned short* M = (y < k) ? (VTs + (size_t)y * BDTOT)
                                      : (Us + (size_t)(y - k) * BDTOT);
    const uint4* m8 = (const uint4*)(M + segbase);
    const uint4* d8 = (const uint4*)(dgxb + segbase);
    float s0 = 0.f;
    #pragma unroll
    for (int it = 0; it < GRP8 / 256; ++it) {
        int g = it * 256 + tid;
        float mv[8], dv[8];
        ub8(m8[g], mv); ub8(d8[g], dv);
        #pragma unroll
        for (int j = 0; j < 8; ++j) s0 = fmaf(mv[j], dv[j], s0);
    }
    __shared__ float r0[256];
    r0[tid] = s0;
    __syncthreads();
    for (int st = 128; st > 0; st >>= 1) {
        if (tid < st) r0[tid] += r0[tid + st];
        __syncthreads();
    }
    if (tid == 0) tparts[((size_t)y * NB + b) * SMAX + s] = r0[0];
}

// ---------------------------------------------------------------------------
// Fused big pass. Every block redundantly folds (deterministic): q_i,r_i
// (tparts), t_i = q_i + tp_r, h_i = r_i + hp_r, p_i (parr_r), 6 state
// scalars (cparts), den, c, flag. Main: one history read, write new rows,
// advance x, mirrors, best snapshot. Block (0,b): O(k^2) recurrences for
// next-iter p (Gram UU) and prev-dot arrays tp_w/hp_w; obj_arr.
// grid = (64, NB), 256 thr, 8 elems/thread.
// ---------------------------------------------------------------------------
__global__ __launch_bounds__(256) void pass2_kernel(
    unsigned short* __restrict__ Us, unsigned short* __restrict__ VTs,
    unsigned short* updb,                 // rw: dx in, new update out
    const unsigned short* __restrict__ dgxb, const unsigned short* __restrict__ gxb,
    float* xv, unsigned short* __restrict__ zb, unsigned short* __restrict__ bestzb,
    const float* __restrict__ tparts, const float* __restrict__ cparts,
    const float* __restrict__ objinit,
    const float* __restrict__ parr_r, float* __restrict__ parr_w,
    const float* __restrict__ tp_r, float* __restrict__ tp_w,
    const float* __restrict__ hp_r, float* __restrict__ hp_w,
    float* __restrict__ UU, float* __restrict__ obj_arr, int k)
{
    const int b = blockIdx.y;
    const int bx = blockIdx.x;
    const int tid = threadIdx.x;
    const int lane = tid & 63, wv = tid >> 6;

    __shared__ float sq[KMAX], st[KMAX], sp[KMAX], sr[KMAX], sh[KMAX], UUk[KMAX];
    __shared__ float sS[5];     // 0:dd 1:dg1 2:dxdx 3:dgdg 4:dgg
    __shared__ float sden, sc, sflag, sobj, srk;
    __shared__ float red[256];

    // ---- fold obj_cur = sum over cparts row 2 (all NB) ----
    {
        float o = 0.f;
        const float* OB = cparts + (size_t)2 * NB * CBLK;
        for (int j = tid; j < NB * CBLK; j += 256) o += OB[j];
        red[tid] = o;
        __syncthreads();
        for (int s = 128; s > 0; s >>= 1) {
            if (tid < s) red[tid] += red[tid + s];
            __syncthreads();
        }
        if (tid == 0) sobj = red[0];
        __syncthreads();
    }
    // ---- k==0: fold obj0 from objinit ----
    float obj0 = 0.f;
    if (k == 0) {
        float o = 0.f;
        for (int j = tid; j < 1024; j += 256) o += objinit[j];
        red[tid] = o;
        __syncthreads();
        for (int s = 128; s > 0; s >>= 1) {
            if (tid < s) red[tid] += red[tid + s];
            __syncthreads();
        }
        obj0 = red[0];
        __syncthreads();
    }

    // ---- per-row folds ----
    if (tid < k) {
        float qv = 0.f, rv = 0.f;
        #pragma unroll
        for (int s = 0; s < SMAX; ++s) {
            qv += tparts[((size_t)tid * NB + b) * SMAX + s];
            rv += tparts[((size_t)(k + tid) * NB + b) * SMAX + s];
        }
        sq[tid] = qv; sr[tid] = rv;
        st[tid] = qv + tp_r[b * KMAX + tid];
        sh[tid] = rv + hp_r[b * KMAX + tid];
        sp[tid] = parr_r[b * KMAX + tid];
    }
    // wave folds of cparts rows (per-batch b)
    if (wv == 1) {
        float a0 = 0.f, a1 = 0.f;
        for (int j = lane; j < CBLK; j += 64) {
            a0 += cparts[((size_t)0 * NB + b) * CBLK + j];
            a1 += cparts[((size_t)3 * NB + b) * CBLK + j];
        }
        a0 = wred(a0); a1 = wred(a1);
        if (lane == 0) { sS[0] = a0; sS[2] = a1; }
    } else if (wv == 2) {
        float a0 = 0.f, a1 = 0.f;
        for (int j = lane; j < CBLK; j += 64) {
            a0 += cparts[((size_t)1 * NB + b) * CBLK + j];
            a1 += cparts[((size_t)4 * NB + b) * CBLK + j];
        }
        a0 = wred(a0); a1 = wred(a1);
        if (lane == 0) { sS[1] = a0; sS[3] = a1; }
    } else if (wv == 3) {
        float a0 = 0.f;
        for (int j = lane; j < CBLK; j += 64)
            a0 += cparts[((size_t)5 * NB + b) * CBLK + j];
        a0 = wred(a0);
        if (lane == 0) sS[4] = a0;
    }
    __syncthreads();

    if (tid == 0) {
        float pq = 0.f, pt = 0.f;
        for (int i = 0; i < k; ++i) { pq += sp[i] * sq[i]; pt += sp[i] * st[i]; }
        float den = -sS[0] + pq;
        if (fabsf(den) < 1e-9f) den = 1e-9f;
        sden = den;
        float rk = -sS[1] + pt;
        srk = rk;
        sc = rk / den;
        float best;
        if (k == 0) best = obj0;
        else {
            best = obj_arr[0];
            for (int j = 1; j <= k; ++j) best = fminf(best, obj_arr[j]);
        }
        sflag = (sobj < best) ? 1.f : 0.f;
    }
    __syncthreads();

    // ------------------- main vector pass -------------------
    const size_t base = (size_t)b * DDIM + ((size_t)bx * 256 + tid) * 8;
    float xd[8], dg[8], gv[8];
    ub8(*(const uint4*)(updb + base), xd);
    ub8(*(const uint4*)(dgxb + base), dg);
    ub8(*(const uint4*)(gxb  + base), gv);

    float S1[8], S2[8], SV[8];
    #pragma unroll
    for (int j = 0; j < 8; ++j) { S1[j] = 0.f; S2[j] = 0.f; SV[j] = 0.f; }

    int i = 0;
    for (; i + 1 < k; i += 2) {
        uint4 ru0 = *(const uint4*)(Us  + (size_t)i * BDTOT + base);
        uint4 rv0 = *(const uint4*)(VTs + (size_t)i * BDTOT + base);
        uint4 ru1 = *(const uint4*)(Us  + (size_t)(i + 1) * BDTOT + base);
        uint4 rv1 = *(const uint4*)(VTs + (size_t)(i + 1) * BDTOT + base);
        float u0[8], v0[8], u1[8], v1[8];
        ub8(ru0, u0); ub8(rv0, v0); ub8(ru1, u1); ub8(rv1, v1);
        float q0 = sq[i], t0 = st[i], p0 = sp[i];
        float q1 = sq[i+1], t1 = st[i+1], p1 = sp[i+1];
        #pragma unroll
        for (int j = 0; j < 8; ++j) {
            S1[j] = fmaf(q0, u0[j], fmaf(q1, u1[j], S1[j]));
            S2[j] = fmaf(t0, u0[j], fmaf(t1, u1[j], S2[j]));
            SV[j] = fmaf(p0, v0[j], fmaf(p1, v1[j], SV[j]));
        }
    }
    if (i < k) {
        float uvals[8], vvals[8];
        ub8(*(const uint4*)(Us  + (size_t)i * BDTOT + base), uvals);
        ub8(*(const uint4*)(VTs + (size_t)i * BDTOT + base), vvals);
        float qi = sq[i], ti = st[i], pi = sp[i];
        #pragma unroll
        for (int j = 0; j < 8; ++j) {
            S1[j] = fmaf(qi, uvals[j], S1[j]);
            S2[j] = fmaf(ti, uvals[j], S2[j]);
            SV[j] = fmaf(pi, vvals[j], SV[j]);
        }
    }

    float vk[8], uk[8], up[8];
    #pragma unroll
    for (int j = 0; j < 8; ++j) {
        vk[j] = -xd[j] + SV[j];
        uk[j] = (xd[j] + dg[j] - S1[j]) / sden;
        up[j] = gv[j] - sc * (xd[j] + dg[j]) - S2[j] + sc * S1[j];
    }
    uint4 vks = {packbf(vk[0],vk[1]), packbf(vk[2],vk[3]), packbf(vk[4],vk[5]), packbf(vk[6],vk[7])};
    uint4 uks = {packbf(uk[0],uk[1]), packbf(uk[2],uk[3]), packbf(uk[4],uk[5]), packbf(uk[6],uk[7])};
    *(uint4*)(VTs + (size_t)k * BDTOT + base) = vks;
    *(uint4*)(Us  + (size_t)k * BDTOT + base) = uks;

    uint4 upw = {packbf(up[0],up[1]), packbf(up[2],up[3]), packbf(up[4],up[5]), packbf(up[6],up[7])};
    *(uint4*)(updb + base) = upw;
    float upr[8];
    ub8(upw, upr);

    float xc[8];
    #pragma unroll
    for (int h = 0; h < 2; ++h) {
        float4 a = *(const float4*)(xv + base + h * 4);
        xc[h*4+0]=a.x; xc[h*4+1]=a.y; xc[h*4+2]=a.z; xc[h*4+3]=a.w;
    }
    if (sflag != 0.f) {
        uint4 bz = {packbf(xc[0],xc[1]), packbf(xc[2],xc[3]),
                    packbf(xc[4],xc[5]), packbf(xc[6],xc[7])};
        *(uint4*)(bestzb + base) = bz;
    }
    float xn[8];
    #pragma unroll
    for (int j = 0; j < 8; ++j) xn[j] = xc[j] + upr[j];
    #pragma unroll
    for (int h = 0; h < 2; ++h)
        *(float4*)(xv + base + h * 4) = make_float4(xn[h*4+0], xn[h*4+1], xn[h*4+2], xn[h*4+3]);
    uint4 zn = {packbf(xn[0],xn[1]), packbf(xn[2],xn[3]), packbf(xn[4],xn[5]), packbf(xn[6],xn[7])};
    *(uint4*)(zb + base) = zn;

    // ------------- scalar recurrences (block bx==0 only) -------------
    if (bx == 0) {
        const float den = sden, cc = sc;
        // UUk[l] = u_k . u_l = ((p_l + r_l) - sum_j q_j UU[b][j][l]) / den
        if (tid < k) {
            float acc = sp[tid] + sr[tid];
            for (int j = 0; j < k; ++j)
                acc -= sq[j] * UU[((size_t)b * KMAX + j) * KMAX + tid];
            UUk[tid] = acc / den;
        }
        __syncthreads();
        if (tid == 0) {
            float ww = sS[2] + 2.f * sS[0] + sS[3];   // w.w
            float wg = sS[1] + sS[4];                 // w.g
            float sumqh = 0.f, sumqpr = 0.f, sumqU = 0.f;
            for (int j = 0; j < k; ++j) {
                sumqh += sq[j] * sh[j];
                sumqpr += sq[j] * (sp[j] + sr[j]);
                sumqU += sq[j] * UUk[j];
            }
            float ug = (wg - sumqh) / den;            // u_k.g
            float uw = (ww - sumqpr) / den;           // u_k.w
            float UUkk = (uw - sumqU) / den;
            for (int l = 0; l < k; ++l) {
                UU[((size_t)b * KMAX + k) * KMAX + l] = UUk[l];
                UU[((size_t)b * KMAX + l) * KMAX + k] = UUk[l];
            }
            UU[((size_t)b * KMAX + k) * KMAX + k] = UUkk;
            // p_next for new row k
            float acc = ug - cc * uw;
            for (int l = 0; l < k; ++l)
                acc -= (st[l] - cc * sq[l]) * UUk[l];
            parr_w[b * KMAX + k] = acc;
            // prev-dot arrays for new row k
            tp_w[b * KMAX + k] = srk;                 // v_k.g
            hp_w[b * KMAX + k] = ug;                  // u_k.g
            if (b == 0) {
                if (k == 0) obj_arr[0] = obj0;
                obj_arr[k + 1] = sobj;
            }
        }
        if (tid < k) {
            // p_next_i = h_i - c (p_i + r_i) - sum_l s_l UU[b][i][l]
            float acc = sh[tid] - cc * (sp[tid] + sr[tid]);
            for (int l = 0; l < k; ++l)
                acc -= (st[l] - cc * sq[l]) * UU[((size_t)b * KMAX + tid) * KMAX + l];
            parr_w[b * KMAX + tid] = acc;
            tp_w[b * KMAX + tid] = st[tid];
            hp_w[b * KMAX + tid] = sh[tid];
        }
    }
}

// ---------------------------------------------------------------------------
// Last iteration: fold obj, flag vs obj_arr[0..KMAX-1], conditional copy.
// ---------------------------------------------------------------------------
__global__ __launch_bounds__(256) void bestfinal_kernel(
    const float* __restrict__ cparts, const float* __restrict__ obj_arr,
    const unsigned short* __restrict__ zb, unsigned short* __restrict__ bestzb)
{
    const int tid = threadIdx.x;
    __shared__ float red[256];
    __shared__ float sflag;
    float o = 0.f;
    const float* OB = cparts + (size_t)2 * NB * CBLK;
    for (int j = tid; j < NB * CBLK; j += 256) o += OB[j];
    red[tid] = o;
    __syncthreads();
    for (int s = 128; s > 0; s >>= 1) {
        if (tid < s) red[tid] += red[tid + s];
        __syncthreads();
    }
    if (tid == 0) {
        float best = obj_arr[0];
        for (int j = 1; j < KMAX; ++j) best = fminf(best, obj_arr[j]);
        sflag = (red[0] < best) ? 1.f : 0.f;
    }
    __syncthreads();
    if (sflag == 0.f) return;
    size_t i = ((size_t)blockIdx.x * 256 + tid) * 8;
    *(uint4*)(bestzb + i) = *(const uint4*)(zb + i);
}

// ---------------------------------------------------------------------------
extern "C" void kernel_launch(void* const* d_in, const int* in_sizes, int n_in,
                              void* d_out, int out_size, void* d_ws, size_t ws_size,
                              hipStream_t stream)
{
    (void)in_sizes; (void)n_in; (void)out_size; (void)ws_size;
    const float* x  = (const float*)d_in[0];   // [16,64,32,32]
    const float* A  = (const float*)d_in[1];   // [128,128,3,3]
    const float* U  = (const float*)d_in[2];   // [128,64,3,3]
    const float* bb = (const float*)d_in[3];   // [128]
    float* out = (float*)d_out;

    char* w = (char*)d_ws;
    size_t off = 0;
    auto alloc = [&](size_t bytes) -> void* {
        void* pp = (void*)(w + off);
        off += (bytes + 255) & ~(size_t)255;
        return pp;
    };
    const size_t BDB  = BDTOT * sizeof(float);  // 8 MB
    const size_t BDH  = BDTOT * 2;              // 4 MB (bf16)
    float* ux    = (float*)alloc(BDB);          // fp32 (final recompute)
    float* xv    = (float*)alloc(BDB);          // fp32 iterate accumulator
    unsigned short* uxb    = (unsigned short*)alloc(BDH);
    unsigned short* gxb    = (unsigned short*)alloc(BDH);
    unsigned short* updb   = (unsigned short*)alloc(BDH);
    unsigned short* dgxb   = (unsigned short*)alloc(BDH);
    unsigned short* zb     = (unsigned short*)alloc(BDH);
    unsigned short* bestzb = (unsigned short*)alloc(BDH);
    unsigned short* xinb   = (unsigned short*)alloc((size_t)NB * PLANE_ * CIN_ * 2);
    unsigned short* WA     = (unsigned short*)alloc((size_t)NWA * 2);
    unsigned short* WU     = (unsigned short*)alloc((size_t)NWU * 2);
    unsigned short* Us  = (unsigned short*)alloc((size_t)KMAX * BDTOT * 2); // 84 MB
    unsigned short* VTs = (unsigned short*)alloc((size_t)KMAX * BDTOT * 2); // 84 MB
    float* cparts = (float*)alloc((size_t)6 * NB * CBLK * sizeof(float));
    float* tparts = (float*)alloc((size_t)2 * KMAX * NB * SMAX * sizeof(float));
    float* objinit= (float*)alloc(1024 * sizeof(float));
    float* parr0 = (float*)alloc(NB * KMAX * sizeof(float));
    float* parr1 = (float*)alloc(NB * KMAX * sizeof(float));
    float* tp0   = (float*)alloc(NB * KMAX * sizeof(float));
    float* tp1   = (float*)alloc(NB * KMAX * sizeof(float));
    float* hp0   = (float*)alloc(NB * KMAX * sizeof(float));
    float* hp1   = (float*)alloc(NB * KMAX * sizeof(float));
    float* UU    = (float*)alloc((size_t)NB * KMAX * KMAX * sizeof(float));
    float* obj_arr = (float*)alloc((KMAX + 1) * sizeof(float));

    const dim3 CG(32, 4, NB);                   // conv grid, 64-thr blocks
    const int I8WG = (int)(BDTOT / (256 * 8));  // 1024 blocks, 8 elems/thread

    // -------- one-time prep --------
    prep_w_kernel<<<(NWA + NWU + 255) / 256, 256, 0, stream>>>(A, U, WA, WU);
    prep_xin_kernel<<<(NB * PLANE_ * CIN_) / 256, 256, 0, stream>>>(x, xinb);
    fill0_kernel<<<(int)(BDH / (256 * 16)), 256, 0, stream>>>((float*)bestzb); // best = x0 = 0

    conv_ux_kernel<<<CG, 64, 0, stream>>>(xinb, WU, bb, ux, uxb);
    ew_init_kernel<<<I8WG, 256, 0, stream>>>(ux, gxb, updb, xv, zb, objinit);

    float* parr[2] = {parr0, parr1};
    float* tp[2]   = {tp0, tp1};
    float* hp[2]   = {hp0, hp1};
    for (int k = 0; k < KMAX; ++k) {
        conv_bro_kernel<<<CG, 64, 0, stream>>>(zb, WA, uxb, xv, gxb, updb, dgxb, cparts);
        if (k < KMAX - 1) {
            if (k > 0)
                dots_kernel<<<dim3(NB, 2 * k, SMAX), 256, 0, stream>>>(
                    Us, VTs, dgxb, tparts, k);
            pass2_kernel<<<dim3(DDIM / 2048, NB), 256, 0, stream>>>(
                Us, VTs, updb, dgxb, gxb, xv, zb, bestzb,
                tparts, cparts, objinit,
                parr[k & 1], parr[(k + 1) & 1],
                tp[k & 1], tp[(k + 1) & 1],
                hp[k & 1], hp[(k + 1) & 1],
                UU, obj_arr, k);
        } else {
            bestfinal_kernel<<<I8WG, 256, 0, stream>>>(cparts, obj_arr, zb, bestzb);
        }
    }

    // zn = relu(conv(best,A) + ux_fp32) -> NCHW out
    conv_final_kernel<<<CG, 64, 0, stream>>>(bestzb, WA, ux, out);
}

// Round 11
// 1348.199 us; speedup vs baseline: 1.4684x; 1.1978x over previous
//
#include <hip/hip_runtime.h>

// Problem constants (fixed by reference setup_inputs)
#define NB    16              // batch
#define CIN_  64              // input channels of x
#define COUT_ 128             // channels of z / output
#define PLANE_ 1024           // 32*32
#define DDIM  (COUT_*PLANE_)  // 131072
#define BDTOT ((size_t)NB*DDIM) // 2097152
#define KMAX  20              // Broyden threshold
#define SMAX  16              // split-K for dots
#define SEG   (DDIM / SMAX)   // 8192
#define GRP8  (SEG / 8)       // 1024 8-elem groups per segment
#define CBLK  128             // conv partial slots per batch (32 hrow x 4 coT)
#define PADC  8               // LDS channel pad (keeps 16B align, spreads banks)

typedef short  bfrag __attribute__((ext_vector_type(8)));  // 8 bf16 (4 VGPRs)
typedef float  ffrag __attribute__((ext_vector_type(4)));  // 4 fp32 acc

// bf16 <-> fp32 helpers (RNE)
__device__ __forceinline__ float bf2f(unsigned short h) {
    return __uint_as_float(((unsigned int)h) << 16);
}
__device__ __forceinline__ unsigned short f2bf(float f) {
    unsigned int u = __float_as_uint(f);
    u = (u + 0x7FFFu + ((u >> 16) & 1u)) >> 16;
    return (unsigned short)u;
}
__device__ __forceinline__ void bf2x(unsigned int w, float& lo, float& hi) {
    lo = __uint_as_float(w << 16);
    hi = __uint_as_float(w & 0xffff0000u);
}
__device__ __forceinline__ unsigned int packbf(float lo, float hi) {
    return ((unsigned int)f2bf(hi) << 16) | (unsigned int)f2bf(lo);
}
__device__ __forceinline__ void ub4(ushort4 a, float* f) {
    f[0] = bf2f(a.x); f[1] = bf2f(a.y); f[2] = bf2f(a.z); f[3] = bf2f(a.w);
}
__device__ __forceinline__ ushort4 pk4(const float* f) {
    ushort4 r; r.x = f2bf(f[0]); r.y = f2bf(f[1]); r.z = f2bf(f[2]); r.w = f2bf(f[3]);
    return r;
}
__device__ __forceinline__ void ub8(uint4 a, float* f) {
    bf2x(a.x, f[0], f[1]); bf2x(a.y, f[2], f[3]);
    bf2x(a.z, f[4], f[5]); bf2x(a.w, f[6], f[7]);
}
__device__ __forceinline__ float wred(float v) {
    #pragma unroll
    for (int m = 32; m > 0; m >>= 1) v += __shfl_xor(v, m, 64);
    return v;
}

// ---------------------------------------------------------------------------
// LDS-staged conv: block (256 thr) = one (hrow, n); stages 3 rows x 34 px
// (w-halo zero-padded) x CIN into LDS once; wave wv computes coT = wv tile
// (32co x 32px) with borderless ds_read_b128 B-fragments. A from L2 (hot).
// ---------------------------------------------------------------------------
template<int CIN>
__device__ __forceinline__ void conv_stage_lds(
    const unsigned short* __restrict__ zsrc, unsigned short* lds,
    int hrow, int n, int tid)
{
    const int CP = CIN + PADC;
    const int CH8 = CIN / 8;
    for (int idx = tid; idx < 102 * CH8; idx += 256) {   // 3*34 slots
        int slot = idx / CH8, chunk = idx - slot * CH8;
        int row = slot / 34, pxm = slot - row * 34;
        int h = hrow + row - 1, w = pxm - 1;
        uint4 val = {0u, 0u, 0u, 0u};
        if ((unsigned)h < 32u && (unsigned)w < 32u)
            val = *(const uint4*)(zsrc + ((size_t)n * PLANE_ + h * 32 + w) * CIN + chunk * 8);
        *(uint4*)(lds + (slot)*CP + chunk * 8) = val;
    }
    __syncthreads();
}

template<int CIN>
__device__ __forceinline__ void conv_compute_lds(
    const unsigned short* lds, const unsigned short* __restrict__ Wt,
    int co_base, int col, int quad, ffrag accs[4])
{
    const int CP = CIN + PADC;
    #pragma unroll
    for (int cb = 0; cb < CIN; cb += 32) {
        #pragma unroll
        for (int tap = 0; tap < 9; ++tap) {
            const int dh = tap / 3, dwi = tap % 3;        // 0..2
            const unsigned short* wr0 =
                Wt + ((size_t)tap * COUT_ + co_base + col) * CIN + quad * 8 + cb;
            bfrag a0 = *(const bfrag*)(wr0);
            bfrag a1 = *(const bfrag*)(wr0 + 16 * CIN);
            bfrag b0 = *(const bfrag*)(lds + (dh * 34 + col + dwi) * CP + cb + quad * 8);
            bfrag b1 = *(const bfrag*)(lds + (dh * 34 + col + 16 + dwi) * CP + cb + quad * 8);
            accs[0] = __builtin_amdgcn_mfma_f32_16x16x32_bf16(a0, b0, accs[0], 0, 0, 0);
            accs[1] = __builtin_amdgcn_mfma_f32_16x16x32_bf16(a0, b1, accs[1], 0, 0, 0);
            accs[2] = __builtin_amdgcn_mfma_f32_16x16x32_bf16(a1, b0, accs[2], 0, 0, 0);
            accs[3] = __builtin_amdgcn_mfma_f32_16x16x32_bf16(a1, b1, accs[3], 0, 0, 0);
        }
    }
}

// ---------------------------------------------------------------------------
// ux = conv(x,U) + b : fp32 ux + bf16 uxb. grid (32, NB), 256 thr.
// ---------------------------------------------------------------------------
__global__ __launch_bounds__(256) void conv_ux_kernel(
    const unsigned short* __restrict__ xinb, const unsigned short* __restrict__ WU,
    const float* __restrict__ bias, float* __restrict__ ux,
    unsigned short* __restrict__ uxb)
{
    __shared__ unsigned short lds[3 * 34 * (CIN_ + PADC)];
    const int hrow = blockIdx.x, n = blockIdx.y;
    const int tid = threadIdx.x, lane = tid & 63, wv = tid >> 6;
    const int col = lane & 15, quad = lane >> 4;
    conv_stage_lds<CIN_>(xinb, lds, hrow, n, tid);
    ffrag accs[4] = {{0.f,0.f,0.f,0.f},{0.f,0.f,0.f,0.f},{0.f,0.f,0.f,0.f},{0.f,0.f,0.f,0.f}};
    conv_compute_lds<CIN_>(lds, WU, wv * 32, col, quad, accs);
    #pragma unroll
    for (int f = 0; f < 4; ++f) {
        const int mt = f >> 1, nt = f & 1;
        const int co = wv * 32 + mt * 16 + quad * 4;
        const int px = hrow * 32 + nt * 16 + col;
        const size_t o = ((size_t)n * PLANE_ + px) * COUT_ + co;
        float4 bv = *(const float4*)(bias + co);
        float r[4] = {accs[f][0] + bv.x, accs[f][1] + bv.y, accs[f][2] + bv.z, accs[f][3] + bv.w};
        *(float4*)(ux + o) = make_float4(r[0], r[1], r[2], r[3]);
        *(ushort4*)(uxb + o) = pk4(r);
    }
}

// ---------------------------------------------------------------------------
// Broyden conv: g = relu(conv(z,A)+ux) - x ; dgx = g - gx_old (gx in place)
// + 6 state scalars: 0:dx.dgx 1:dx.g 2:g.g 3:dx.dx 4:dgx.dgx 5:dgx.g
// cparts[(row*NB+n)*CBLK + blk], blk = hrow*4+wv. grid (32, NB), 256 thr.
// ---------------------------------------------------------------------------
__global__ __launch_bounds__(256) void conv_bro_kernel(
    const unsigned short* __restrict__ zb, const unsigned short* __restrict__ WA,
    const unsigned short* __restrict__ uxb, const float* __restrict__ xv,
    unsigned short* gxb,                       // rw (old -> new)
    const unsigned short* __restrict__ updb,   // dx
    unsigned short* __restrict__ dgxb,
    float* __restrict__ cparts)
{
    __shared__ unsigned short lds[3 * 34 * (COUT_ + PADC)];
    const int hrow = blockIdx.x, n = blockIdx.y;
    const int tid = threadIdx.x, lane = tid & 63, wv = tid >> 6;
    const int col = lane & 15, quad = lane >> 4;
    conv_stage_lds<COUT_>(zb, lds, hrow, n, tid);
    ffrag accs[4] = {{0.f,0.f,0.f,0.f},{0.f,0.f,0.f,0.f},{0.f,0.f,0.f,0.f},{0.f,0.f,0.f,0.f}};
    conv_compute_lds<COUT_>(lds, WA, wv * 32, col, quad, accs);

    float s0 = 0.f, s1 = 0.f, s2 = 0.f, s3 = 0.f, s4 = 0.f, s5 = 0.f;
    #pragma unroll
    for (int f = 0; f < 4; ++f) {
        const int mt = f >> 1, nt = f & 1;
        const int co = wv * 32 + mt * 16 + quad * 4;
        const int px = hrow * 32 + nt * 16 + col;
        const size_t o = ((size_t)n * PLANE_ + px) * COUT_ + co;
        float uxv[4], gov[4], udv[4];
        ub4(*(const ushort4*)(uxb + o), uxv);
        ub4(*(const ushort4*)(gxb + o), gov);
        ub4(*(const ushort4*)(updb + o), udv);
        float4 xc = *(const float4*)(xv + o);
        float g[4], dgv[4];
        #pragma unroll
        for (int r = 0; r < 4; ++r) {
            float tv = accs[f][r] + uxv[r];
            tv = tv > 0.f ? tv : 0.f;
            g[r] = tv - (&xc.x)[r];
            dgv[r] = g[r] - gov[r];
            s0 += udv[r] * dgv[r];
            s1 += udv[r] * g[r];
            s2 += g[r] * g[r];
            s3 += udv[r] * udv[r];
            s4 += dgv[r] * dgv[r];
            s5 += dgv[r] * g[r];
        }
        *(ushort4*)(gxb + o)  = pk4(g);
        *(ushort4*)(dgxb + o) = pk4(dgv);
    }
    s0 = wred(s0); s1 = wred(s1); s2 = wred(s2);
    s3 = wred(s3); s4 = wred(s4); s5 = wred(s5);
    if (lane == 0) {
        const int blk = hrow * 4 + wv;
        cparts[((size_t)0 * NB + n) * CBLK + blk] = s0;
        cparts[((size_t)1 * NB + n) * CBLK + blk] = s1;
        cparts[((size_t)2 * NB + n) * CBLK + blk] = s2;
        cparts[((size_t)3 * NB + n) * CBLK + blk] = s3;
        cparts[((size_t)4 * NB + n) * CBLK + blk] = s4;
        cparts[((size_t)5 * NB + n) * CBLK + blk] = s5;
    }
}

// ---------------------------------------------------------------------------
// Final recompute: out = relu(conv(best,A) + ux_fp32)  -> NCHW
// ---------------------------------------------------------------------------
__global__ __launch_bounds__(256) void conv_final_kernel(
    const unsigned short* __restrict__ bestzb, const unsigned short* __restrict__ WA,
    const float* __restrict__ ux, float* __restrict__ out)
{
    __shared__ unsigned short lds[3 * 34 * (COUT_ + PADC)];
    const int hrow = blockIdx.x, n = blockIdx.y;
    const int tid = threadIdx.x, lane = tid & 63, wv = tid >> 6;
    const int col = lane & 15, quad = lane >> 4;
    conv_stage_lds<COUT_>(bestzb, lds, hrow, n, tid);
    ffrag accs[4] = {{0.f,0.f,0.f,0.f},{0.f,0.f,0.f,0.f},{0.f,0.f,0.f,0.f},{0.f,0.f,0.f,0.f}};
    conv_compute_lds<COUT_>(lds, WA, wv * 32, col, quad, accs);
    #pragma unroll
    for (int f = 0; f < 4; ++f) {
        const int mt = f >> 1, nt = f & 1;
        const int co = wv * 32 + mt * 16 + quad * 4;
        const int px = hrow * 32 + nt * 16 + col;
        const size_t o = ((size_t)n * PLANE_ + px) * COUT_ + co;
        float4 uv = *(const float4*)(ux + o);
        #pragma unroll
        for (int r = 0; r < 4; ++r) {
            float t = accs[f][r] + (&uv.x)[r];
            out[((size_t)n * COUT_ + co + r) * PLANE_ + px] = t > 0.f ? t : 0.f;
        }
    }
}

// ---------------------------------------------------------------------------
// One-time prep
// ---------------------------------------------------------------------------
#define NWA (9 * 128 * 128)
#define NWU (9 * 128 * 64)
__global__ __launch_bounds__(256) void prep_w_kernel(
    const float* __restrict__ A, const float* __restrict__ U,
    unsigned short* __restrict__ WA, unsigned short* __restrict__ WU)
{
    int idx = blockIdx.x * 256 + threadIdx.x;
    if (idx < NWA) {
        int tap = idx / (128 * 128), r = idx % (128 * 128);
        int co = r >> 7, ci = r & 127;
        WA[idx] = f2bf(A[(co * 128 + ci) * 9 + tap]);
    } else if (idx < NWA + NWU) {
        int j = idx - NWA;
        int tap = j / (128 * 64), r = j % (128 * 64);
        int co = r >> 6, ci = r & 63;
        WU[j] = f2bf(U[(co * 64 + ci) * 9 + tap]);
    }
}

__global__ __launch_bounds__(256) void prep_xin_kernel(
    const float* __restrict__ x, unsigned short* __restrict__ xb)
{
    int idx = blockIdx.x * 256 + threadIdx.x;   // over 16*1024*64
    int n = idx >> 16, r = idx & 65535;
    int px = r >> 6, ci = r & 63;
    xb[idx] = f2bf(x[(n * 64 + ci) * 1024 + px]);
}

__global__ __launch_bounds__(256) void fill0_kernel(float* __restrict__ a)
{
    size_t i = ((size_t)blockIdx.x * 256 + threadIdx.x) * 4;
    *(float4*)(a + i) = make_float4(0.f, 0.f, 0.f, 0.f);
}

// ---------------------------------------------------------------------------
// Init: gx0 = upd0 = relu(ux) (bf16-rounded), x1 = same (fp32), zb mirror,
// per-block obj partial -> objinit[1024].
// ---------------------------------------------------------------------------
__global__ __launch_bounds__(256) void ew_init_kernel(
    const float* __restrict__ ux, unsigned short* __restrict__ gxb,
    unsigned short* __restrict__ updb, float* __restrict__ xv,
    unsigned short* __restrict__ zb, float* __restrict__ objinit)
{
    const int tid = threadIdx.x;
    size_t i = ((size_t)blockIdx.x * 256 + tid) * 8;
    float rr[8];
    float ob = 0.f;
    #pragma unroll
    for (int h = 0; h < 2; ++h) {
        float4 u = *(const float4*)(ux + i + h * 4);
        #pragma unroll
        for (int r = 0; r < 4; ++r) {
            float v = (&u.x)[r];
            v = v > 0.f ? v : 0.f;
            v = bf2f(f2bf(v));           // round once, use consistently
            rr[h*4+r] = v;
            ob += v * v;
        }
    }
    uint4 m = {packbf(rr[0],rr[1]), packbf(rr[2],rr[3]), packbf(rr[4],rr[5]), packbf(rr[6],rr[7])};
    *(uint4*)(gxb  + i) = m;
    *(uint4*)(updb + i) = m;
    *(uint4*)(zb   + i) = m;
    #pragma unroll
    for (int h = 0; h < 2; ++h)
        *(float4*)(xv + i + h * 4) = make_float4(rr[h*4+0], rr[h*4+1], rr[h*4+2], rr[h*4+3]);

    __shared__ float so[256];
    so[tid] = ob;
    __syncthreads();
    for (int s = 128; s > 0; s >>= 1) {
        if (tid < s) so[tid] += so[tid + s];
        __syncthreads();
    }
    if (tid == 0) objinit[blockIdx.x] = so[0];
}

// ---------------------------------------------------------------------------
// Split-K dots vs dgx ONLY: y<k: q_i = v_i.dgx ; y>=k: r_i = u_i.dgx
// grid (NB, 2k, SMAX), 256 thr. tparts[(y*NB+b)*SMAX+s]
// ---------------------------------------------------------------------------
__global__ __launch_bounds__(256) void dots_kernel(
    const unsigned short* __restrict__ Us, const unsigned short* __restrict__ VTs,
    const unsigned short* __restrict__ dgxb,
    float* __restrict__ tparts, int k)
{
    const int b = blockIdx.x, y = blockIdx.y, s = blockIdx.z;
    const int tid = threadIdx.x;
    const size_t segbase = (size_t)b * DDIM + (size_t)s * SEG;
    const unsigned short* M = (y < k) ? (VTs + (size_t)y * BDTOT)
                                      : (Us + (size_t)(y - k) * BDTOT);
    const uint4* m8 = (const uint4*)(M + segbase);
    const uint4* d8 = (const uint4*)(dgxb + segbase);
    float s0 = 0.f;
    #pragma unroll
    for (int it = 0; it < GRP8 / 256; ++it) {
        int g = it * 256 + tid;
        float mv[8], dv[8];
        ub8(m8[g], mv); ub8(d8[g], dv);
        #pragma unroll
        for (int j = 0; j < 8; ++j) s0 = fmaf(mv[j], dv[j], s0);
    }
    __shared__ float r0[256];
    r0[tid] = s0;
    __syncthreads();
    for (int st = 128; st > 0; st >>= 1) {
        if (tid < st) r0[tid] += r0[tid + st];
        __syncthreads();
    }
    if (tid == 0) tparts[((size_t)y * NB + b) * SMAX + s] = r0[0];
}

// ---------------------------------------------------------------------------
// Fused big pass. Every block redundantly folds (deterministic): q_i,r_i
// (tparts), t_i = q_i + tp_r, h_i = r_i + hp_r, p_i (parr_r), 6 state
// scalars (cparts), den, c, flag. Main: one history read, write new rows,
// advance x, mirrors, best snapshot. Block (0,b): O(k^2) recurrences for
// next-iter p (Gram UU) and prev-dot arrays tp_w/hp_w; obj_arr.
// grid = (64, NB), 256 thr, 8 elems/thread.
// ---------------------------------------------------------------------------
__global__ __launch_bounds__(256) void pass2_kernel(
    unsigned short* __restrict__ Us, unsigned short* __restrict__ VTs,
    unsigned short* updb,                 // rw: dx in, new update out
    const unsigned short* __restrict__ dgxb, const unsigned short* __restrict__ gxb,
    float* xv, unsigned short* __restrict__ zb, unsigned short* __restrict__ bestzb,
    const float* __restrict__ tparts, const float* __restrict__ cparts,
    const float* __restrict__ objinit,
    const float* __restrict__ parr_r, float* __restrict__ parr_w,
    const float* __restrict__ tp_r, float* __restrict__ tp_w,
    const float* __restrict__ hp_r, float* __restrict__ hp_w,
    float* __restrict__ UU, float* __restrict__ obj_arr, int k)
{
    const int b = blockIdx.y;
    const int bx = blockIdx.x;
    const int tid = threadIdx.x;
    const int lane = tid & 63, wv = tid >> 6;

    __shared__ float sq[KMAX], st[KMAX], sp[KMAX], sr[KMAX], sh[KMAX], UUk[KMAX];
    __shared__ float sS[5];     // 0:dd 1:dg1 2:dxdx 3:dgdg 4:dgg
    __shared__ float sden, sc, sflag, sobj, srk;
    __shared__ float red[256];

    // ---- fold obj_cur = sum over cparts row 2 (all NB) ----
    {
        float o = 0.f;
        const float* OB = cparts + (size_t)2 * NB * CBLK;
        for (int j = tid; j < NB * CBLK; j += 256) o += OB[j];
        red[tid] = o;
        __syncthreads();
        for (int s = 128; s > 0; s >>= 1) {
            if (tid < s) red[tid] += red[tid + s];
            __syncthreads();
        }
        if (tid == 0) sobj = red[0];
        __syncthreads();
    }
    // ---- k==0: fold obj0 from objinit ----
    float obj0 = 0.f;
    if (k == 0) {
        float o = 0.f;
        for (int j = tid; j < 1024; j += 256) o += objinit[j];
        red[tid] = o;
        __syncthreads();
        for (int s = 128; s > 0; s >>= 1) {
            if (tid < s) red[tid] += red[tid + s];
            __syncthreads();
        }
        obj0 = red[0];
        __syncthreads();
    }

    // ---- per-row folds ----
    if (tid < k) {
        float qv = 0.f, rv = 0.f;
        #pragma unroll
        for (int s = 0; s < SMAX; ++s) {
            qv += tparts[((size_t)tid * NB + b) * SMAX + s];
            rv += tparts[((size_t)(k + tid) * NB + b) * SMAX + s];
        }
        sq[tid] = qv; sr[tid] = rv;
        st[tid] = qv + tp_r[b * KMAX + tid];
        sh[tid] = rv + hp_r[b * KMAX + tid];
        sp[tid] = parr_r[b * KMAX + tid];
    }
    // wave folds of cparts rows (per-batch b)
    if (wv == 1) {
        float a0 = 0.f, a1 = 0.f;
        for (int j = lane; j < CBLK; j += 64) {
            a0 += cparts[((size_t)0 * NB + b) * CBLK + j];
            a1 += cparts[((size_t)3 * NB + b) * CBLK + j];
        }
        a0 = wred(a0); a1 = wred(a1);
        if (lane == 0) { sS[0] = a0; sS[2] = a1; }
    } else if (wv == 2) {
        float a0 = 0.f, a1 = 0.f;
        for (int j = lane; j < CBLK; j += 64) {
            a0 += cparts[((size_t)1 * NB + b) * CBLK + j];
            a1 += cparts[((size_t)4 * NB + b) * CBLK + j];
        }
        a0 = wred(a0); a1 = wred(a1);
        if (lane == 0) { sS[1] = a0; sS[3] = a1; }
    } else if (wv == 3) {
        float a0 = 0.f;
        for (int j = lane; j < CBLK; j += 64)
            a0 += cparts[((size_t)5 * NB + b) * CBLK + j];
        a0 = wred(a0);
        if (lane == 0) sS[4] = a0;
    }
    __syncthreads();

    if (tid == 0) {
        float pq = 0.f, pt = 0.f;
        for (int i = 0; i < k; ++i) { pq += sp[i] * sq[i]; pt += sp[i] * st[i]; }
        float den = -sS[0] + pq;
        if (fabsf(den) < 1e-9f) den = 1e-9f;
        sden = den;
        float rk = -sS[1] + pt;
        srk = rk;
        sc = rk / den;
        float best;
        if (k == 0) best = obj0;
        else {
            best = obj_arr[0];
            for (int j = 1; j <= k; ++j) best = fminf(best, obj_arr[j]);
        }
        sflag = (sobj < best) ? 1.f : 0.f;
    }
    __syncthreads();

    // ------------------- main vector pass -------------------
    const size_t base = (size_t)b * DDIM + ((size_t)bx * 256 + tid) * 8;
    float xd[8], dg[8], gv[8];
    ub8(*(const uint4*)(updb + base), xd);
    ub8(*(const uint4*)(dgxb + base), dg);
    ub8(*(const uint4*)(gxb  + base), gv);

    float S1[8], S2[8], SV[8];
    #pragma unroll
    for (int j = 0; j < 8; ++j) { S1[j] = 0.f; S2[j] = 0.f; SV[j] = 0.f; }

    int i = 0;
    for (; i + 1 < k; i += 2) {
        uint4 ru0 = *(const uint4*)(Us  + (size_t)i * BDTOT + base);
        uint4 rv0 = *(const uint4*)(VTs + (size_t)i * BDTOT + base);
        uint4 ru1 = *(const uint4*)(Us  + (size_t)(i + 1) * BDTOT + base);
        uint4 rv1 = *(const uint4*)(VTs + (size_t)(i + 1) * BDTOT + base);
        float u0[8], v0[8], u1[8], v1[8];
        ub8(ru0, u0); ub8(rv0, v0); ub8(ru1, u1); ub8(rv1, v1);
        float q0 = sq[i], t0 = st[i], p0 = sp[i];
        float q1 = sq[i+1], t1 = st[i+1], p1 = sp[i+1];
        #pragma unroll
        for (int j = 0; j < 8; ++j) {
            S1[j] = fmaf(q0, u0[j], fmaf(q1, u1[j], S1[j]));
            S2[j] = fmaf(t0, u0[j], fmaf(t1, u1[j], S2[j]));
            SV[j] = fmaf(p0, v0[j], fmaf(p1, v1[j], SV[j]));
        }
    }
    if (i < k) {
        float uvals[8], vvals[8];
        ub8(*(const uint4*)(Us  + (size_t)i * BDTOT + base), uvals);
        ub8(*(const uint4*)(VTs + (size_t)i * BDTOT + base), vvals);
        float qi = sq[i], ti = st[i], pi = sp[i];
        #pragma unroll
        for (int j = 0; j < 8; ++j) {
            S1[j] = fmaf(qi, uvals[j], S1[j]);
            S2[j] = fmaf(ti, uvals[j], S2[j]);
            SV[j] = fmaf(pi, vvals[j], SV[j]);
        }
    }

    float vk[8], uk[8], up[8];
    #pragma unroll
    for (int j = 0; j < 8; ++j) {
        vk[j] = -xd[j] + SV[j];
        uk[j] = (xd[j] + dg[j] - S1[j]) / sden;
        up[j] = gv[j] - sc * (xd[j] + dg[j]) - S2[j] + sc * S1[j];
    }
    uint4 vks = {packbf(vk[0],vk[1]), packbf(vk[2],vk[3]), packbf(vk[4],vk[5]), packbf(vk[6],vk[7])};
    uint4 uks = {packbf(uk[0],uk[1]), packbf(uk[2],uk[3]), packbf(uk[4],uk[5]), packbf(uk[6],uk[7])};
    *(uint4*)(VTs + (size_t)k * BDTOT + base) = vks;
    *(uint4*)(Us  + (size_t)k * BDTOT + base) = uks;

    uint4 upw = {packbf(up[0],up[1]), packbf(up[2],up[3]), packbf(up[4],up[5]), packbf(up[6],up[7])};
    *(uint4*)(updb + base) = upw;
    float upr[8];
    ub8(upw, upr);

    float xc[8];
    #pragma unroll
    for (int h = 0; h < 2; ++h) {
        float4 a = *(const float4*)(xv + base + h * 4);
        xc[h*4+0]=a.x; xc[h*4+1]=a.y; xc[h*4+2]=a.z; xc[h*4+3]=a.w;
    }
    if (sflag != 0.f) {
        uint4 bz = {packbf(xc[0],xc[1]), packbf(xc[2],xc[3]),
                    packbf(xc[4],xc[5]), packbf(xc[6],xc[7])};
        *(uint4*)(bestzb + base) = bz;
    }
    float xn[8];
    #pragma unroll
    for (int j = 0; j < 8; ++j) xn[j] = xc[j] + upr[j];
    #pragma unroll
    for (int h = 0; h < 2; ++h)
        *(float4*)(xv + base + h * 4) = make_float4(xn[h*4+0], xn[h*4+1], xn[h*4+2], xn[h*4+3]);
    uint4 zn = {packbf(xn[0],xn[1]), packbf(xn[2],xn[3]), packbf(xn[4],xn[5]), packbf(xn[6],xn[7])};
    *(uint4*)(zb + base) = zn;

    // ------------- scalar recurrences (block bx==0 only) -------------
    if (bx == 0) {
        const float den = sden, cc = sc;
        // UUk[l] = u_k . u_l = ((p_l + r_l) - sum_j q_j UU[b][j][l]) / den
        if (tid < k) {
            float acc = sp[tid] + sr[tid];
            for (int j = 0; j < k; ++j)
                acc -= sq[j] * UU[((size_t)b * KMAX + j) * KMAX + tid];
            UUk[tid] = acc / den;
        }
        __syncthreads();
        if (tid == 0) {
            float ww = sS[2] + 2.f * sS[0] + sS[3];   // w.w
            float wg = sS[1] + sS[4];                 // w.g
            float sumqh = 0.f, sumqpr = 0.f, sumqU = 0.f;
            for (int j = 0; j < k; ++j) {
                sumqh += sq[j] * sh[j];
                sumqpr += sq[j] * (sp[j] + sr[j]);
                sumqU += sq[j] * UUk[j];
            }
            float ug = (wg - sumqh) / den;            // u_k.g
            float uw = (ww - sumqpr) / den;           // u_k.w
            float UUkk = (uw - sumqU) / den;
            for (int l = 0; l < k; ++l) {
                UU[((size_t)b * KMAX + k) * KMAX + l] = UUk[l];
                UU[((size_t)b * KMAX + l) * KMAX + k] = UUk[l];
            }
            UU[((size_t)b * KMAX + k) * KMAX + k] = UUkk;
            // p_next for new row k
            float acc = ug - cc * uw;
            for (int l = 0; l < k; ++l)
                acc -= (st[l] - cc * sq[l]) * UUk[l];
            parr_w[b * KMAX + k] = acc;
            // prev-dot arrays for new row k
            tp_w[b * KMAX + k] = srk;                 // v_k.g
            hp_w[b * KMAX + k] = ug;                  // u_k.g
            if (b == 0) {
                if (k == 0) obj_arr[0] = obj0;
                obj_arr[k + 1] = sobj;
            }
        }
        if (tid < k) {
            // p_next_i = h_i - c (p_i + r_i) - sum_l s_l UU[b][i][l]
            float acc = sh[tid] - cc * (sp[tid] + sr[tid]);
            for (int l = 0; l < k; ++l)
                acc -= (st[l] - cc * sq[l]) * UU[((size_t)b * KMAX + tid) * KMAX + l];
            parr_w[b * KMAX + tid] = acc;
            tp_w[b * KMAX + tid] = st[tid];
            hp_w[b * KMAX + tid] = sh[tid];
        }
    }
}

// ---------------------------------------------------------------------------
// Last iteration: fold obj, flag vs obj_arr[0..KMAX-1], conditional copy.
// ---------------------------------------------------------------------------
__global__ __launch_bounds__(256) void bestfinal_kernel(
    const float* __restrict__ cparts, const float* __restrict__ obj_arr,
    const unsigned short* __restrict__ zb, unsigned short* __restrict__ bestzb)
{
    const int tid = threadIdx.x;
    __shared__ float red[256];
    __shared__ float sflag;
    float o = 0.f;
    const float* OB = cparts + (size_t)2 * NB * CBLK;
    for (int j = tid; j < NB * CBLK; j += 256) o += OB[j];
    red[tid] = o;
    __syncthreads();
    for (int s = 128; s > 0; s >>= 1) {
        if (tid < s) red[tid] += red[tid + s];
        __syncthreads();
    }
    if (tid == 0) {
        float best = obj_arr[0];
        for (int j = 1; j < KMAX; ++j) best = fminf(best, obj_arr[j]);
        sflag = (red[0] < best) ? 1.f : 0.f;
    }
    __syncthreads();
    if (sflag == 0.f) return;
    size_t i = ((size_t)blockIdx.x * 256 + tid) * 8;
    *(uint4*)(bestzb + i) = *(const uint4*)(zb + i);
}

// ---------------------------------------------------------------------------
extern "C" void kernel_launch(void* const* d_in, const int* in_sizes, int n_in,
                              void* d_out, int out_size, void* d_ws, size_t ws_size,
                              hipStream_t stream)
{
    (void)in_sizes; (void)n_in; (void)out_size; (void)ws_size;
    const float* x  = (const float*)d_in[0];   // [16,64,32,32]
    const float* A  = (const float*)d_in[1];   // [128,128,3,3]
    const float* U  = (const float*)d_in[2];   // [128,64,3,3]
    const float* bb = (const float*)d_in[3];   // [128]
    float* out = (float*)d_out;

    char* w = (char*)d_ws;
    size_t off = 0;
    auto alloc = [&](size_t bytes) -> void* {
        void* pp = (void*)(w + off);
        off += (bytes + 255) & ~(size_t)255;
        return pp;
    };
    const size_t BDB  = BDTOT * sizeof(float);  // 8 MB
    const size_t BDH  = BDTOT * 2;              // 4 MB (bf16)
    float* ux    = (float*)alloc(BDB);          // fp32 (final recompute)
    float* xv    = (float*)alloc(BDB);          // fp32 iterate accumulator
    unsigned short* uxb    = (unsigned short*)alloc(BDH);
    unsigned short* gxb    = (unsigned short*)alloc(BDH);
    unsigned short* updb   = (unsigned short*)alloc(BDH);
    unsigned short* dgxb   = (unsigned short*)alloc(BDH);
    unsigned short* zb     = (unsigned short*)alloc(BDH);
    unsigned short* bestzb = (unsigned short*)alloc(BDH);
    unsigned short* xinb   = (unsigned short*)alloc((size_t)NB * PLANE_ * CIN_ * 2);
    unsigned short* WA     = (unsigned short*)alloc((size_t)NWA * 2);
    unsigned short* WU     = (unsigned short*)alloc((size_t)NWU * 2);
    unsigned short* Us  = (unsigned short*)alloc((size_t)KMAX * BDTOT * 2); // 84 MB
    unsigned short* VTs = (unsigned short*)alloc((size_t)KMAX * BDTOT * 2); // 84 MB
    float* cparts = (float*)alloc((size_t)6 * NB * CBLK * sizeof(float));
    float* tparts = (float*)alloc((size_t)2 * KMAX * NB * SMAX * sizeof(float));
    float* objinit= (float*)alloc(1024 * sizeof(float));
    float* parr0 = (float*)alloc(NB * KMAX * sizeof(float));
    float* parr1 = (float*)alloc(NB * KMAX * sizeof(float));
    float* tp0   = (float*)alloc(NB * KMAX * sizeof(float));
    float* tp1   = (float*)alloc(NB * KMAX * sizeof(float));
    float* hp0   = (float*)alloc(NB * KMAX * sizeof(float));
    float* hp1   = (float*)alloc(NB * KMAX * sizeof(float));
    float* UU    = (float*)alloc((size_t)NB * KMAX * KMAX * sizeof(float));
    float* obj_arr = (float*)alloc((KMAX + 1) * sizeof(float));

    const dim3 CG(32, NB);                      // conv grid, 256-thr blocks
    const int I8WG = (int)(BDTOT / (256 * 8));  // 1024 blocks, 8 elems/thread

    // -------- one-time prep --------
    prep_w_kernel<<<(NWA + NWU + 255) / 256, 256, 0, stream>>>(A, U, WA, WU);
    prep_xin_kernel<<<(NB * PLANE_ * CIN_) / 256, 256, 0, stream>>>(x, xinb);
    fill0_kernel<<<(int)(BDH / (256 * 16)), 256, 0, stream>>>((float*)bestzb); // best = x0 = 0

    conv_ux_kernel<<<CG, 256, 0, stream>>>(xinb, WU, bb, ux, uxb);
    ew_init_kernel<<<I8WG, 256, 0, stream>>>(ux, gxb, updb, xv, zb, objinit);

    float* parr[2] = {parr0, parr1};
    float* tp[2]   = {tp0, tp1};
    float* hp[2]   = {hp0, hp1};
    for (int k = 0; k < KMAX; ++k) {
        conv_bro_kernel<<<CG, 256, 0, stream>>>(zb, WA, uxb, xv, gxb, updb, dgxb, cparts);
        if (k < KMAX - 1) {
            if (k > 0)
                dots_kernel<<<dim3(NB, 2 * k, SMAX), 256, 0, stream>>>(
                    Us, VTs, dgxb, tparts, k);
            pass2_kernel<<<dim3(DDIM / 2048, NB), 256, 0, stream>>>(
                Us, VTs, updb, dgxb, gxb, xv, zb, bestzb,
                tparts, cparts, objinit,
                parr[k & 1], parr[(k + 1) & 1],
                tp[k & 1], tp[(k + 1) & 1],
                hp[k & 1], hp[(k + 1) & 1],
                UU, obj_arr, k);
        } else {
            bestfinal_kernel<<<I8WG, 256, 0, stream>>>(cparts, obj_arr, zb, bestzb);
        }
    }

    // zn = relu(conv(best,A) + ux_fp32) -> NCHW out
    conv_final_kernel<<<CG, 256, 0, stream>>>(bestzb, WA, ux, out);
}